// Round 8
// baseline (56253.577 us; speedup 1.0000x reference)
//
#include <hip/hip_runtime.h>
#include <math.h>

#define BS   16384
#define HID  1024
#define G4   4096
#define EMB  512
#define WVD  300
#define IND  812
#define VOC  258
#define NST  14
#define WPLANE 4194304   /* 4096*1024 */

typedef int i32x4 __attribute__((ext_vector_type(4)));

__device__ __forceinline__ double dsig(double x){ return 1.0/(1.0+exp(-x)); }
__device__ __forceinline__ double dtanh_(double x){
  double ax = fabs(x);
  double e = exp(-2.0*ax);
  double t = (1.0-e)/(1.0+e);
  return x < 0.0 ? -t : t;
}

// ---------------- E = emb @ W_ih[:, :512].T -> f64 [VOC][G4] ----------------
#define ETT 16
__global__ __launch_bounds__(256) void ekernel_f64(const float* __restrict__ emb,
                                                   const float* __restrict__ Wih,
                                                   double* __restrict__ E){
  __shared__ float elds[ETT][EMB];
  const int tid = threadIdx.x;
  const int n  = blockIdx.x*256 + tid;
  const int t0 = blockIdx.y*ETT;
  #pragma unroll
  for (int i = 0; i < 8; ++i){
    int fi = tid + 256*i;
    int tt = fi >> 7;
    int kk = (fi & 127) << 2;
    float4 v = make_float4(0.f,0.f,0.f,0.f);
    if (t0+tt < VOC) v = *(const float4*)(emb + (size_t)(t0+tt)*EMB + kk);
    *(float4*)&elds[tt][kk] = v;
  }
  __syncthreads();
  double acc[ETT];
  #pragma unroll
  for (int tt=0;tt<ETT;++tt) acc[tt]=0.0;
  const float* wr = Wih + (size_t)n*IND;
  for (int k=0;k<EMB;k+=4){
    float4 w = *(const float4*)(wr + k);
    double w0=w.x, w1=w.y, w2=w.z, w3=w.w;
    #pragma unroll
    for (int tt=0;tt<ETT;++tt){
      float4 e = *(const float4*)&elds[tt][k];
      acc[tt] += (double)e.x*w0 + (double)e.y*w1 + (double)e.z*w2 + (double)e.w*w3;
    }
  }
  #pragma unroll
  for (int tt=0;tt<ETT;++tt){
    int t = t0+tt;
    if (t < VOC) E[(size_t)t*G4 + n] = acc[tt];
  }
}

// ---------------- base = wv @ Wih[:,512:].T + b_ih + b_hh -> f64 [R][G4] ----------------
__global__ __launch_bounds__(256) void base_v3(const float* __restrict__ wv,
                                               const float* __restrict__ Wih,
                                               const float* __restrict__ bih,
                                               const float* __restrict__ bhh,
                                               double* __restrict__ base){
  __shared__ float Al[32][132];
  __shared__ float Bl[32][132];
  const int tid = threadIdx.x;
  const int r0 = blockIdx.x*128, n0 = blockIdx.y*128;
  const int tx = tid & 15, ty = tid >> 4;
  double acc[8][8];
  #pragma unroll
  for (int i=0;i<8;++i)
    #pragma unroll
    for (int j=0;j<8;++j) acc[i][j]=0.0;

  const int ra = tid >> 1, kb16 = (tid & 1) * 16;
  for (int t = 0; t < 10; ++t){
    int k0 = t*32;
    #pragma unroll
    for (int j=0;j<16;++j){
      int k = k0 + kb16 + j;
      Al[kb16+j][ra] = (k < WVD) ? wv[(size_t)(r0+ra)*WVD + k] : 0.f;
      Bl[kb16+j][ra] = (k < WVD) ? Wih[(size_t)(n0+ra)*IND + EMB + k] : 0.f;
    }
    __syncthreads();
    #pragma unroll
    for (int k=0;k<32;++k){
      double av[8], bv[8];
      #pragma unroll
      for (int i=0;i<8;++i) av[i] = (double)Al[k][ty*8+i];
      #pragma unroll
      for (int j=0;j<8;++j) bv[j] = (double)Bl[k][tx + 16*j];
      #pragma unroll
      for (int i=0;i<8;++i)
        #pragma unroll
        for (int j=0;j<8;++j) acc[i][j] += av[i]*bv[j];
    }
    __syncthreads();
  }
  #pragma unroll
  for (int i=0;i<8;++i){
    int r = r0 + ty*8 + i;
    #pragma unroll
    for (int j=0;j<8;++j){
      int n = n0 + tx + 16*j;
      base[(size_t)r*G4 + n] = acc[i][j] + (double)bih[n] + (double)bhh[n];
    }
  }
}

// ---------------- W slices: Whh f32 -> 5 signed base-256 digit planes (exact) ----------------
__global__ __launch_bounds__(256) void wslice(const float* __restrict__ W,
                                              signed char* __restrict__ wsl){
  const int flat = (blockIdx.x*256 + threadIdx.x)*4;   // over 4096*1024
  float4 w = *(const float4*)(W + flat);
  float we[4] = {w.x, w.y, w.z, w.w};
  unsigned int pack[5] = {0,0,0,0,0};
  #pragma unroll
  for (int e=0;e<4;++e){
    long long n = __double2ll_rn((double)we[e] * 1099511627776.0);  // 2^40
    #pragma unroll
    for (int s=4;s>=1;--s){
      int d = (int)(((n + 128) & 255) - 128);
      pack[s] |= ((unsigned int)(unsigned char)d) << (8*e);
      n = (n - d) >> 8;
    }
    pack[0] |= ((unsigned int)(unsigned char)(int)n) << (8*e);
  }
  #pragma unroll
  for (int s=0;s<5;++s)
    *(unsigned int*)(wsl + (size_t)s*WPLANE + flat) = pack[s];
}

// ---------------- h slices: h f64 -> 6 signed base-256 digit planes (scale 2^46) ----------------
__global__ __launch_bounds__(256) void slice_h(const double* __restrict__ h,
                                               signed char* __restrict__ hs, int hplane){
  const long long flat = ((long long)blockIdx.x*256 + threadIdx.x)*8;
  double v[8];
  #pragma unroll
  for (int q=0;q<4;++q)
    *(double2*)&v[2*q] = *(const double2*)(h + flat + 2*q);
  unsigned long long pack[6] = {0,0,0,0,0,0};
  #pragma unroll
  for (int e=0;e<8;++e){
    long long n = __double2ll_rn(v[e] * 70368744177664.0);   // 2^46
    #pragma unroll
    for (int s=5;s>=1;--s){
      int d = (int)(((n + 128) & 255) - 128);
      pack[s] |= ((unsigned long long)(unsigned char)d) << (8*e);
      n = (n - d) >> 8;
    }
    pack[0] |= ((unsigned long long)(unsigned char)(int)n) << (8*e);
  }
  #pragma unroll
  for (int s=0;s<6;++s)
    *(unsigned long long*)(hs + (size_t)s*hplane + flat) = pack[s];
}

// ---------------- gates via i8 MFMA (exact i32 accumulate) + f64 combine + fused LSTM cell ----
// block 256 thr = 4 waves (2m x 2n). tile: 32 rows x 16 units (= 64 gate-cols).
// wave (wm,wn): rows r0+wm*16..+15, gates {2wn,2wn+1} of units u0..u0+15.
// gate = W x h: h digits i=0..5 (weight 2^{40-8i}, scale 2^46), W digits j=0..4 (2^{32-8j}, 2^40).
// pairs i+j<=5 (20). val = sum_s psum_s 2^{-14-8s}.
__global__ __launch_bounds__(256) void gates_i8(
    const signed char* __restrict__ hs, const signed char* __restrict__ wsl,
    double* __restrict__ hout, double* __restrict__ cst,
    const int* __restrict__ idx, const double* __restrict__ E,
    const double* __restrict__ base, int nht, int hplane)
{
  constexpr int PI[20] = {0,0,0,0,0, 1,1,1,1,1, 2,2,2,2, 3,3,3, 4,4, 5};
  constexpr int PJ[20] = {0,1,2,3,4, 0,1,2,3,4, 0,1,2,3, 0,1,2, 0,1, 0};
  constexpr int PS[20] = {0,1,2,3,4, 1,2,3,4,5, 2,3,4,5, 3,4,5, 4,5, 5};
  __shared__ double gx[4][32][17];
  const int tid = threadIdx.x;
  const int lane = tid & 63, wid = tid >> 6;
  const int l15 = lane & 15, l4 = lane >> 4;
  const int wm = wid >> 1, wn = wid & 1;
  // 16x16 supertile swizzle for L2 locality
  const int f = blockIdx.x + gridDim.x*blockIdx.y;
  const int nclx = gridDim.x >> 4;
  const int st = f >> 8, w8 = f & 255;
  const int rb = (st % nclx)*16 + (w8 & 15);
  const int cb = (st / nclx)*16 + (w8 >> 4);
  const int r0 = rb*32, u0 = cb*16;

  i32x4 acc0[20], acc1[20];
  #pragma unroll
  for (int p=0;p<20;++p){ acc0[p] = (i32x4)(0); acc1[p] = (i32x4)(0); }
  asm volatile("s_nop 3" ::);   // VALU-write -> MFMA SrcC hazard guard

  const int rowA = r0 + wm*16 + l15;
  const size_t wr0 = (size_t)((2*wn)*HID + u0 + l15);
  const signed char* ap  = hs  + (size_t)rowA*1024 + l4*16;
  const signed char* bp0 = wsl + wr0*1024 + l4*16;
  const signed char* bp1 = bp0 + (size_t)HID*1024;

  for (int t = 0; t < nht; ++t){
    const int k0 = t*64;
    i32x4 a[6], b[5];
    #pragma unroll
    for (int i=0;i<6;++i) a[i] = *(const i32x4*)(ap + (size_t)i*hplane + k0);
    #pragma unroll
    for (int j=0;j<5;++j) b[j] = *(const i32x4*)(bp0 + (size_t)j*WPLANE + k0);
    #pragma unroll
    for (int p=0;p<20;++p)
      asm("v_mfma_i32_16x16x64_i8 %0, %1, %2, %0" : "+v"(acc0[p]) : "v"(a[PI[p]]), "v"(b[PJ[p]]));
    #pragma unroll
    for (int j=0;j<5;++j) b[j] = *(const i32x4*)(bp1 + (size_t)j*WPLANE + k0);
    #pragma unroll
    for (int p=0;p<20;++p)
      asm("v_mfma_i32_16x16x64_i8 %0, %1, %2, %0" : "+v"(acc1[p]) : "v"(a[PI[p]]), "v"(b[PJ[p]]));
  }
  asm volatile("s_nop 7\n\ts_nop 7\n\ts_nop 7" ::);  // MFMA -> VALU read hazard guard

  // combine digit-pair accumulators -> f64 gate pre-activations, stage in LDS
  #pragma unroll
  for (int nt=0;nt<2;++nt){
    #pragma unroll
    for (int e=0;e<4;++e){
      int ps[6] = {0,0,0,0,0,0};
      #pragma unroll
      for (int p=0;p<20;++p){
        int v = nt ? acc1[p][e] : acc0[p][e];
        ps[PS[p]] += v;
      }
      double val = (double)ps[5];
      val = val*0.00390625 + (double)ps[4];
      val = val*0.00390625 + (double)ps[3];
      val = val*0.00390625 + (double)ps[2];
      val = val*0.00390625 + (double)ps[1];
      val = val*0.00390625 + (double)ps[0];
      val *= 6.103515625e-05;   // 2^-14
      gx[2*wn+nt][wm*16 + l4*4 + e][l15] = val;
    }
  }
  __syncthreads();

  // fused LSTM cell: thread -> (row, unit) x2
  const int uu = tid & 15, rr = tid >> 4;
  #pragma unroll
  for (int half=0; half<2; ++half){
    const int lrow = rr + half*16;
    const int r = r0 + lrow;
    const int u = u0 + uu;
    const int tok = idx[r];
    const double* Er = E + (size_t)tok*G4;
    const double* Br = base + (size_t)r*G4;
    double pre[4];
    #pragma unroll
    for (int g=0;g<4;++g) pre[g] = gx[g][lrow][uu] + Er[g*HID+u] + Br[g*HID+u];
    double co = cst[(size_t)r*HID + u];
    double cn = dsig(pre[1])*co + dsig(pre[0])*dtanh_(pre[2]);
    double hn = dsig(pre[3])*dtanh_(cn);
    cst[(size_t)r*HID + u]  = cn;
    hout[(size_t)r*HID + u] = hn;
  }
}

// ---------------- fused gates GEMM f64 fallback (R7 version) ----------------
__global__ __launch_bounds__(256) void gates_v3(
    const double* __restrict__ hin, double* __restrict__ hout,
    double* __restrict__ cst, const int* __restrict__ idx,
    const double* __restrict__ E, const double* __restrict__ base,
    const float* __restrict__ Whh, const float* __restrict__ Wih,
    const float* __restrict__ wv,
    const float* __restrict__ bih, const float* __restrict__ bhh,
    int nht, int nwt)
{
  __shared__ double Al[32][132];
  __shared__ float  Bl[32][132];
  const int tid = threadIdx.x;
  const int r0 = blockIdx.x * 128;
  const int u0 = blockIdx.y * 32;
  const int tx = tid & 15, ty = tid >> 4;
  double acc[8][8];
  #pragma unroll
  for (int i=0;i<8;++i)
    #pragma unroll
    for (int j=0;j<8;++j) acc[i][j]=0.0;

  const int ra   = tid >> 1, kb16 = (tid & 1) * 16;
  const int cb   = ra;
  const int wrow = (cb >> 5)*HID + u0 + (cb & 31);

  for (int t = 0; t < nht + nwt; ++t){
    if (t < nht){
      int k0 = t*32;
      const double* s0 = hin + (size_t)(r0+ra)*HID + k0 + kb16;
      #pragma unroll
      for (int jj=0;jj<8;++jj){
        double2 v = *(const double2*)(s0 + 2*jj);
        Al[kb16+2*jj  ][ra] = v.x;
        Al[kb16+2*jj+1][ra] = v.y;
      }
      const float* s1 = Whh + (size_t)wrow*HID + k0 + kb16;
      #pragma unroll
      for (int jj=0;jj<4;++jj){
        float4 w = *(const float4*)(s1 + 4*jj);
        Bl[kb16+4*jj  ][cb] = w.x;
        Bl[kb16+4*jj+1][cb] = w.y;
        Bl[kb16+4*jj+2][cb] = w.z;
        Bl[kb16+4*jj+3][cb] = w.w;
      }
    } else {
      int k0 = (t - nht)*32;
      #pragma unroll
      for (int j=0;j<16;++j){
        int k = k0 + kb16 + j;
        Al[kb16+j][ra] = (k < WVD) ? (double)wv[(size_t)(r0+ra)*WVD + k] : 0.0;
        Bl[kb16+j][cb] = (k < WVD) ? Wih[(size_t)wrow*IND + EMB + k] : 0.f;
      }
    }
    __syncthreads();
    #pragma unroll
    for (int k=0;k<32;++k){
      double av[8], bv[8];
      #pragma unroll
      for (int i=0;i<8;++i) av[i] = Al[k][ty*8+i];
      #pragma unroll
      for (int j=0;j<8;++j) bv[j] = (double)Bl[k][tx + 16*j];
      #pragma unroll
      for (int i=0;i<8;++i)
        #pragma unroll
        for (int j=0;j<8;++j) acc[i][j] += av[i]*bv[j];
    }
    __syncthreads();
  }

  #pragma unroll
  for (int i=0;i<8;++i){
    int r = r0 + ty*8 + i;
    int tok = idx[r];
    const double* Er = E + (size_t)tok*G4;
    #pragma unroll
    for (int v=0;v<2;++v){
      int u = u0 + tx + 16*v;
      double pre[4];
      if (base){
        const double* Br = base + (size_t)r*G4;
        #pragma unroll
        for (int g=0;g<4;++g) pre[g] = acc[i][2*g+v] + Er[g*HID+u] + Br[g*HID+u];
      } else {
        #pragma unroll
        for (int g=0;g<4;++g) pre[g] = acc[i][2*g+v] + Er[g*HID+u]
                                     + (double)bih[g*HID+u] + (double)bhh[g*HID+u];
      }
      double co = cst[(size_t)r*HID + u];
      double cn = dsig(pre[1])*co + dsig(pre[0])*dtanh_(pre[2]);
      double hn = dsig(pre[3])*dtanh_(cn);
      cst[(size_t)r*HID + u]  = cn;
      hout[(size_t)r*HID + u] = hn;
    }
  }
}

// ---------------- logits partial GEMM (f64 acc, f32-B LDS, BK=32), split-K=3 ----------------
__global__ __launch_bounds__(256) void logits_v3(
    const double* __restrict__ h, const float* __restrict__ Wlin,
    double* __restrict__ lbuf)
{
  __shared__ double Al[32][68];
  __shared__ float  Bl[32][68];
  const int tid = threadIdx.x;
  const int r0 = blockIdx.x*64, n0 = blockIdx.y*64, kk = blockIdx.z;
  const int kt0 = kk*11;
  const int kt1 = (kk==2) ? 32 : kt0 + 11;
  const int tx = tid & 15, ty = tid >> 4;
  double acc[4][4];
  #pragma unroll
  for (int i=0;i<4;++i)
    #pragma unroll
    for (int j=0;j<4;++j) acc[i][j]=0.0;

  const int ra = tid >> 2, kb8 = (tid & 3) * 8;
  const int wr = n0 + ra;
  const bool wok = (wr < VOC);
  for (int t = kt0; t < kt1; ++t){
    int k0 = t*32;
    const double* s0 = h + (size_t)(r0+ra)*HID + k0 + kb8;
    #pragma unroll
    for (int jj=0;jj<4;++jj){
      double2 v = *(const double2*)(s0 + 2*jj);
      Al[kb8+2*jj  ][ra] = v.x;
      Al[kb8+2*jj+1][ra] = v.y;
    }
    if (wok){
      const float* s1 = Wlin + (size_t)wr*HID + k0 + kb8;
      float4 w0 = *(const float4*)(s1+0);
      float4 w1 = *(const float4*)(s1+4);
      Bl[kb8+0][ra] = w0.x; Bl[kb8+1][ra] = w0.y;
      Bl[kb8+2][ra] = w0.z; Bl[kb8+3][ra] = w0.w;
      Bl[kb8+4][ra] = w1.x; Bl[kb8+5][ra] = w1.y;
      Bl[kb8+6][ra] = w1.z; Bl[kb8+7][ra] = w1.w;
    } else {
      #pragma unroll
      for (int j=0;j<8;++j) Bl[kb8+j][ra] = 0.f;
    }
    __syncthreads();
    #pragma unroll
    for (int k=0;k<32;++k){
      double av[4], bv[4];
      #pragma unroll
      for (int i=0;i<4;++i) av[i] = Al[k][ty*4+i];
      #pragma unroll
      for (int j=0;j<4;++j) bv[j] = (double)Bl[k][tx+16*j];
      #pragma unroll
      for (int i=0;i<4;++i)
        #pragma unroll
        for (int j=0;j<4;++j) acc[i][j] += av[i]*bv[j];
    }
    __syncthreads();
  }
  #pragma unroll
  for (int i=0;i<4;++i){
    int r = r0 + ty*4 + i;
    #pragma unroll
    for (int j=0;j<4;++j){
      int n = n0 + tx + 16*j;
      lbuf[(size_t)r*HID + kk*320 + n] = acc[i][j];
    }
  }
}

// ---------------- sum partials + bias, softmax top-1, argmax, next idx ----------------
__global__ __launch_bounds__(256) void argmax_f64(
    const double* __restrict__ lbuf, const float* __restrict__ blin,
    int* __restrict__ idx, float* __restrict__ outp, float* __restrict__ outi)
{
  const int tid = threadIdx.x;
  const int r = blockIdx.x*4 + (tid >> 6);
  const int lane = tid & 63;
  const double* lr = lbuf + (size_t)r*HID;
  double v[5];
  double m = -INFINITY; int am = 0;
  #pragma unroll
  for (int t=0;t<5;++t){
    int col = lane + 64*t;
    if (col < VOC){
      double x = ((lr[col] + lr[320+col]) + lr[640+col]) + (double)blin[col];
      v[t] = x;
      if (x > m){ m = x; am = col; }
    } else v[t] = -INFINITY;
  }
  #pragma unroll
  for (int d=1; d<64; d<<=1){
    double om = __shfl_xor(m, d, 64);
    int   oa = __shfl_xor(am, d, 64);
    if (om > m || (om == m && oa < am)){ m = om; am = oa; }
  }
  double s = 0.0;
  #pragma unroll
  for (int t=0;t<5;++t){
    int col = lane + 64*t;
    if (col < VOC) s += exp(v[t] - m);
  }
  #pragma unroll
  for (int d=1; d<64; d<<=1) s += __shfl_xor(s, d, 64);
  if (lane == 0){
    idx[r]  = am;
    outp[r] = (float)(1.0/s);
    outi[r] = (float)am;
  }
}

// ======================= launch =======================

extern "C" void kernel_launch(void* const* d_in, const int* in_sizes, int n_in,
                              void* d_out, int out_size, void* d_ws, size_t ws_size,
                              hipStream_t stream){
  const float* wv   = (const float*)d_in[0];
  const float* emb  = (const float*)d_in[1];
  const float* Wih  = (const float*)d_in[2];
  const float* Whh  = (const float*)d_in[3];
  const float* bih  = (const float*)d_in[4];
  const float* bhh  = (const float*)d_in[5];
  const float* Wlin = (const float*)d_in[6];
  const float* blin = (const float*)d_in[7];
  float* out = (float*)d_out;

  char* w = (char*)d_ws;
  size_t off = 0;
  auto al = [](size_t b){ return (b + 255) & ~(size_t)255; };
  auto alloc = [&](size_t bytes) -> void* {
    void* p = w + off; off += al(bytes); return p;
  };

  const size_t fixed = al((size_t)VOC*G4*8) + al((size_t)BS*4);

  // tier A-i8 (preferred): base + h/W digit planes + i8 MFMA gates
  int R = 0; int mode = 0;   // 2=i8, 1=f64+base, 0=f64 no-base
  for (int r = 4096; r >= 2048; r >>= 1){
    size_t need = fixed + 3*al((size_t)r*HID*8) + al((size_t)r*G4*8)
                + al((size_t)6*r*HID) + al((size_t)5*WPLANE);
    if (need <= ws_size){ R = r; mode = 2; break; }
  }
  if (!R){
    for (int r = 4096; r >= 1024; r >>= 1){
      if (fixed + 3*al((size_t)r*HID*8) + al((size_t)r*G4*8) <= ws_size){ R = r; mode = 1; break; }
    }
  }
  if (!R){
    for (int r = 8192; r >= 256; r >>= 1){
      if (fixed + 3*al((size_t)r*HID*8) <= ws_size){ R = r; mode = 0; break; }
    }
  }
  if (!R) return;

  double* Ed  = (double*)alloc((size_t)VOC*G4*8);
  int*    idx = (int*)   alloc((size_t)BS*4);
  double* h0  = (double*)alloc((size_t)R*HID*8);
  double* h1  = (double*)alloc((size_t)R*HID*8);
  double* cd  = (double*)alloc((size_t)R*HID*8);
  double* base = (mode >= 1) ? (double*)alloc((size_t)R*G4*8) : nullptr;
  signed char* hs  = (mode == 2) ? (signed char*)alloc((size_t)6*R*HID) : nullptr;
  signed char* wsl = (mode == 2) ? (signed char*)alloc((size_t)5*WPLANE) : nullptr;

  hipMemsetAsync(idx, 0, (size_t)BS*4, stream);
  ekernel_f64<<<dim3(16,17),256,0,stream>>>(emb, Wih, Ed);
  if (mode == 2)
    wslice<<<WPLANE/1024,256,0,stream>>>(Whh, wsl);

  const int hplane = R*HID;
  for (int c0 = 0; c0 < BS; c0 += R){
    if (mode >= 1)
      base_v3<<<dim3(R/128, 32),256,0,stream>>>(wv + (size_t)c0*WVD, Wih, bih, bhh, base);
    hipMemsetAsync(cd, 0, (size_t)R*HID*8, stream);
    double* hb[2] = {h0, h1};
    for (int s = 0; s < NST; ++s){
      if (mode == 2){
        if (s > 0)
          slice_h<<<R/2,256,0,stream>>>(hb[s&1], hs, hplane);
        gates_i8<<<dim3(R/32, 64),256,0,stream>>>(
            hs, wsl, hb[(s+1)&1], cd, idx + c0, Ed, base,
            (s==0) ? 0 : HID/64, hplane);
      } else {
        gates_v3<<<dim3(R/128, 32),256,0,stream>>>(
            hb[s&1], hb[(s+1)&1], cd, idx + c0, Ed, base,
            Whh, Wih, wv + (size_t)c0*WVD, bih, bhh,
            (s==0) ? 0 : HID/32, (mode==1) ? 0 : 10);
      }
      logits_v3<<<dim3(R/64, 5, 3),256,0,stream>>>(
          hb[(s+1)&1], Wlin, hb[s&1]);
      argmax_f64<<<R/4,256,0,stream>>>(
          hb[s&1], blin, idx + c0,
          out + (size_t)s*BS + c0, out + (size_t)NST*BS + (size_t)s*BS + c0);
    }
  }
}

// Round 9
// 51764.050 us; speedup vs baseline: 1.0867x; 1.0867x over previous
//
#include <hip/hip_runtime.h>
#include <math.h>

#define BS   16384
#define HID  1024
#define G4   4096
#define EMB  512
#define WVD  300
#define IND  812
#define VOC  258
#define NST  14
#define WPLANE 4194304            /* 4096*1024 */
#define VOCP 272
#define VLPLANE (VOCP*1024)

typedef int i32x4 __attribute__((ext_vector_type(4)));

#define MFMA8(d, sa, sb) asm("v_mfma_i32_16x16x64_i8 %0, %1, %2, %0" : "+v"(d) : "v"(sa), "v"(sb))

__device__ __forceinline__ double dsig(double x){ return 1.0/(1.0+exp(-x)); }
__device__ __forceinline__ double dtanh_(double x){
  double ax = fabs(x);
  double e = exp(-2.0*ax);
  double t = (1.0-e)/(1.0+e);
  return x < 0.0 ? -t : t;
}

// ---------------- E = emb @ W_ih[:, :512].T -> f64 [VOC][G4] ----------------
#define ETT 16
__global__ __launch_bounds__(256) void ekernel_f64(const float* __restrict__ emb,
                                                   const float* __restrict__ Wih,
                                                   double* __restrict__ E){
  __shared__ float elds[ETT][EMB];
  const int tid = threadIdx.x;
  const int n  = blockIdx.x*256 + tid;
  const int t0 = blockIdx.y*ETT;
  #pragma unroll
  for (int i = 0; i < 8; ++i){
    int fi = tid + 256*i;
    int tt = fi >> 7;
    int kk = (fi & 127) << 2;
    float4 v = make_float4(0.f,0.f,0.f,0.f);
    if (t0+tt < VOC) v = *(const float4*)(emb + (size_t)(t0+tt)*EMB + kk);
    *(float4*)&elds[tt][kk] = v;
  }
  __syncthreads();
  double acc[ETT];
  #pragma unroll
  for (int tt=0;tt<ETT;++tt) acc[tt]=0.0;
  const float* wr = Wih + (size_t)n*IND;
  for (int k=0;k<EMB;k+=4){
    float4 w = *(const float4*)(wr + k);
    double w0=w.x, w1=w.y, w2=w.z, w3=w.w;
    #pragma unroll
    for (int tt=0;tt<ETT;++tt){
      float4 e = *(const float4*)&elds[tt][k];
      acc[tt] += (double)e.x*w0 + (double)e.y*w1 + (double)e.z*w2 + (double)e.w*w3;
    }
  }
  #pragma unroll
  for (int tt=0;tt<ETT;++tt){
    int t = t0+tt;
    if (t < VOC) E[(size_t)t*G4 + n] = acc[tt];
  }
}

// ---------------- base = wv @ Wih[:,512:].T + b_ih + b_hh -> f64 [R][G4] ----------------
__global__ __launch_bounds__(256) void base_v3(const float* __restrict__ wv,
                                               const float* __restrict__ Wih,
                                               const float* __restrict__ bih,
                                               const float* __restrict__ bhh,
                                               double* __restrict__ base){
  __shared__ float Al[32][132];
  __shared__ float Bl[32][132];
  const int tid = threadIdx.x;
  const int r0 = blockIdx.x*128, n0 = blockIdx.y*128;
  const int tx = tid & 15, ty = tid >> 4;
  double acc[8][8];
  #pragma unroll
  for (int i=0;i<8;++i)
    #pragma unroll
    for (int j=0;j<8;++j) acc[i][j]=0.0;

  const int ra = tid >> 1, kb16 = (tid & 1) * 16;
  for (int t = 0; t < 10; ++t){
    int k0 = t*32;
    #pragma unroll
    for (int j=0;j<16;++j){
      int k = k0 + kb16 + j;
      Al[kb16+j][ra] = (k < WVD) ? wv[(size_t)(r0+ra)*WVD + k] : 0.f;
      Bl[kb16+j][ra] = (k < WVD) ? Wih[(size_t)(n0+ra)*IND + EMB + k] : 0.f;
    }
    __syncthreads();
    #pragma unroll
    for (int k=0;k<32;++k){
      double av[8], bv[8];
      #pragma unroll
      for (int i=0;i<8;++i) av[i] = (double)Al[k][ty*8+i];
      #pragma unroll
      for (int j=0;j<8;++j) bv[j] = (double)Bl[k][tx + 16*j];
      #pragma unroll
      for (int i=0;i<8;++i)
        #pragma unroll
        for (int j=0;j<8;++j) acc[i][j] += av[i]*bv[j];
    }
    __syncthreads();
  }
  #pragma unroll
  for (int i=0;i<8;++i){
    int r = r0 + ty*8 + i;
    #pragma unroll
    for (int j=0;j<8;++j){
      int n = n0 + tx + 16*j;
      base[(size_t)r*G4 + n] = acc[i][j] + (double)bih[n] + (double)bhh[n];
    }
  }
}

// ---------------- W slices: f32 -> 5 signed base-256 digit planes (exact, scale 2^40) ----------
__global__ __launch_bounds__(256) void wslice(const float* __restrict__ W,
                                              signed char* __restrict__ out, int plane){
  const int flat = (blockIdx.x*256 + threadIdx.x)*4;
  float4 w = *(const float4*)(W + flat);
  float we[4] = {w.x, w.y, w.z, w.w};
  unsigned int pack[5] = {0,0,0,0,0};
  #pragma unroll
  for (int e=0;e<4;++e){
    long long n = __double2ll_rn((double)we[e] * 1099511627776.0);  // 2^40
    #pragma unroll
    for (int s=4;s>=1;--s){
      int d = (int)(((n + 128) & 255) - 128);
      pack[s] |= ((unsigned int)(unsigned char)d) << (8*e);
      n = (n - d) >> 8;
    }
    pack[0] |= ((unsigned int)(unsigned char)(int)n) << (8*e);
  }
  #pragma unroll
  for (int s=0;s<5;++s)
    *(unsigned int*)(out + (size_t)s*plane + flat) = pack[s];
}

// ---------------- h slices: f64 -> 6 signed base-256 digit planes (scale 2^46) ----------------
__global__ __launch_bounds__(256) void slice_h(const double* __restrict__ h,
                                               signed char* __restrict__ hs, int hplane){
  const long long flat = ((long long)blockIdx.x*256 + threadIdx.x)*8;
  double v[8];
  #pragma unroll
  for (int q=0;q<4;++q)
    *(double2*)&v[2*q] = *(const double2*)(h + flat + 2*q);
  unsigned long long pack[6] = {0,0,0,0,0,0};
  #pragma unroll
  for (int e=0;e<8;++e){
    long long n = __double2ll_rn(v[e] * 70368744177664.0);   // 2^46
    #pragma unroll
    for (int s=5;s>=1;--s){
      int d = (int)(((n + 128) & 255) - 128);
      pack[s] |= ((unsigned long long)(unsigned char)d) << (8*e);
      n = (n - d) >> 8;
    }
    pack[0] |= ((unsigned long long)(unsigned char)(int)n) << (8*e);
  }
  #pragma unroll
  for (int s=0;s<6;++s)
    *(unsigned long long*)(hs + (size_t)s*hplane + flat) = pack[s];
}

#define MFMA20(ACC) \
    MFMA8(ACC[0], a[0], b[0]); \
    MFMA8(ACC[1], a[0], b[1]); \
    MFMA8(ACC[2], a[0], b[2]); \
    MFMA8(ACC[3], a[0], b[3]); \
    MFMA8(ACC[4], a[0], b[4]); \
    MFMA8(ACC[1], a[1], b[0]); \
    MFMA8(ACC[2], a[1], b[1]); \
    MFMA8(ACC[3], a[1], b[2]); \
    MFMA8(ACC[4], a[1], b[3]); \
    MFMA8(ACC[5], a[1], b[4]); \
    MFMA8(ACC[2], a[2], b[0]); \
    MFMA8(ACC[3], a[2], b[1]); \
    MFMA8(ACC[4], a[2], b[2]); \
    MFMA8(ACC[5], a[2], b[3]); \
    MFMA8(ACC[3], a[3], b[0]); \
    MFMA8(ACC[4], a[3], b[1]); \
    MFMA8(ACC[5], a[3], b[2]); \
    MFMA8(ACC[4], a[4], b[0]); \
    MFMA8(ACC[5], a[4], b[1]); \
    MFMA8(ACC[5], a[5], b[0]);

// ---------------- gates via i8 MFMA (s-shared i32 accs) + in-register LSTM cell ----------------
// block 256 thr = 4 waves. block tile: 64 rows x 16 units. wave wid: rows r0+wid*16..+15.
// wave's 4 n-tiles = the 4 GATES of units u0..u0+15 -> each lane ends with all 4 gates
// of (row = r0+wid*16+l4*4+e, unit = u0+l15): cell computed in-register, no LDS.
__global__ __launch_bounds__(256) void gates_i8(
    const signed char* __restrict__ hs, const signed char* __restrict__ wsl,
    double* __restrict__ hout, double* __restrict__ cst,
    const int* __restrict__ idx, const double* __restrict__ E,
    const double* __restrict__ base, int nht, int hplane, int nbx)
{
  const int tid = threadIdx.x;
  const int lane = tid & 63, wid = tid >> 6;
  const int l15 = lane & 15, l4 = lane >> 4;
  // supertile swizzle: 8 u-blocks per group, all row-blocks inside -> B planes L2-resident
  const int f = blockIdx.x + nbx*blockIdx.y;
  const int G = nbx*8;
  const int grp = f / G, wi = f - grp*G;
  const int lbx = wi % nbx, lby = grp*8 + wi/nbx;
  const int r0 = lbx*64, u0 = lby*16;

  i32x4 acc[4][6];
  #pragma unroll
  for (int nt=0;nt<4;++nt)
    #pragma unroll
    for (int s=0;s<6;++s) acc[nt][s] = (i32x4)(0);
  asm volatile("s_nop 3" ::);   // VALU-write -> MFMA SrcC hazard guard

  const int aoff = (r0 + wid*16 + l15)*1024 + l4*16;

  for (int t = 0; t < nht; ++t){
    const int k0 = t*64;
    i32x4 a[6];
    #pragma unroll
    for (int i=0;i<6;++i)
      a[i] = *(const i32x4*)(hs + aoff + i*hplane + k0);
    #pragma unroll
    for (int nt=0;nt<4;++nt){
      const int boff = (nt*HID + u0 + l15)*1024 + l4*16 + k0;
      i32x4 b[5];
      #pragma unroll
      for (int j=0;j<5;++j)
        b[j] = *(const i32x4*)(wsl + boff + j*WPLANE);
      MFMA20(acc[nt]);
    }
  }
  asm volatile("s_nop 7\ns_nop 7\ns_nop 7" ::);  // MFMA -> VALU read hazard guard

  // combine digit sums -> f64 gate pre-activations (weights 2^{-14-8s}, Horner)
  double val[4][4];
  #pragma unroll
  for (int nt=0;nt<4;++nt){
    #pragma unroll
    for (int e=0;e<4;++e){
      double v = (double)acc[nt][5][e];
      v = v*0.00390625 + (double)acc[nt][4][e];
      v = v*0.00390625 + (double)acc[nt][3][e];
      v = v*0.00390625 + (double)acc[nt][2][e];
      v = v*0.00390625 + (double)acc[nt][1][e];
      v = v*0.00390625 + (double)acc[nt][0][e];
      val[nt][e] = v * 6.103515625e-05;   // 2^-14
    }
  }
  const int u = u0 + l15;
  #pragma unroll
  for (int e=0;e<4;++e){
    const int r = r0 + wid*16 + l4*4 + e;
    const int tok = idx[r];
    const double* Er = E + (size_t)tok*G4;
    const double* Br = base + (size_t)r*G4;
    double pre[4];
    #pragma unroll
    for (int g=0;g<4;++g) pre[g] = val[g][e] + Er[g*HID+u] + Br[g*HID+u];
    double co = cst[(size_t)r*HID + u];
    double cn = dsig(pre[1])*co + dsig(pre[0])*dtanh_(pre[2]);
    double hn = dsig(pre[3])*dtanh_(cn);
    cst[(size_t)r*HID + u]  = cn;
    hout[(size_t)r*HID + u] = hn;
  }
}

// ---------------- logits via i8 MFMA: lbuf[r][n] = (Wlin . h)  (no bias) ----------------
// grid (R/64, 17). block tile 64 rows x 16 vocab-cols; wave wid = m-tile.
__global__ __launch_bounds__(256) void logits_i8(
    const signed char* __restrict__ hs, const signed char* __restrict__ wvl,
    double* __restrict__ lbuf, int hplane)
{
  const int tid = threadIdx.x;
  const int lane = tid & 63, wid = tid >> 6;
  const int l15 = lane & 15, l4 = lane >> 4;
  const int r0 = blockIdx.x*64, n0 = blockIdx.y*16;

  i32x4 acc[6];
  #pragma unroll
  for (int s=0;s<6;++s) acc[s] = (i32x4)(0);
  asm volatile("s_nop 3" ::);

  const int aoff = (r0 + wid*16 + l15)*1024 + l4*16;
  const int boff0 = (n0 + l15)*1024 + l4*16;

  for (int t = 0; t < 16; ++t){
    const int k0 = t*64;
    i32x4 a[6], b[5];
    #pragma unroll
    for (int i=0;i<6;++i)
      a[i] = *(const i32x4*)(hs + aoff + i*hplane + k0);
    #pragma unroll
    for (int j=0;j<5;++j)
      b[j] = *(const i32x4*)(wvl + boff0 + j*VLPLANE + k0);
    MFMA20(acc);
  }
  asm volatile("s_nop 7\ns_nop 7\ns_nop 7" ::);

  #pragma unroll
  for (int e=0;e<4;++e){
    double v = (double)acc[5][e];
    v = v*0.00390625 + (double)acc[4][e];
    v = v*0.00390625 + (double)acc[3][e];
    v = v*0.00390625 + (double)acc[2][e];
    v = v*0.00390625 + (double)acc[1][e];
    v = v*0.00390625 + (double)acc[0][e];
    v *= 6.103515625e-05;
    const int r = r0 + wid*16 + l4*4 + e;
    lbuf[(size_t)r*HID + n0 + l15] = v;
  }
}

// ---------------- direct argmax: x = lbuf[r][col] + blin[col] ----------------
__global__ __launch_bounds__(256) void argmax_di(
    const double* __restrict__ lbuf, const float* __restrict__ blin,
    int* __restrict__ idx, float* __restrict__ outp, float* __restrict__ outi)
{
  const int tid = threadIdx.x;
  const int r = blockIdx.x*4 + (tid >> 6);
  const int lane = tid & 63;
  const double* lr = lbuf + (size_t)r*HID;
  double v[5];
  double m = -INFINITY; int am = 0;
  #pragma unroll
  for (int t=0;t<5;++t){
    int col = lane + 64*t;
    if (col < VOC){
      double x = lr[col] + (double)blin[col];
      v[t] = x;
      if (x > m){ m = x; am = col; }
    } else v[t] = -INFINITY;
  }
  #pragma unroll
  for (int d=1; d<64; d<<=1){
    double om = __shfl_xor(m, d, 64);
    int   oa = __shfl_xor(am, d, 64);
    if (om > m || (om == m && oa < am)){ m = om; am = oa; }
  }
  double s = 0.0;
  #pragma unroll
  for (int t=0;t<5;++t){
    int col = lane + 64*t;
    if (col < VOC) s += exp(v[t] - m);
  }
  #pragma unroll
  for (int d=1; d<64; d<<=1) s += __shfl_xor(s, d, 64);
  if (lane == 0){
    idx[r]  = am;
    outp[r] = (float)(1.0/s);
    outi[r] = (float)am;
  }
}

// ================= f64 fallback kernels (R7, proven) =================

__global__ __launch_bounds__(256) void gates_v3(
    const double* __restrict__ hin, double* __restrict__ hout,
    double* __restrict__ cst, const int* __restrict__ idx,
    const double* __restrict__ E, const double* __restrict__ base,
    const float* __restrict__ Whh, const float* __restrict__ Wih,
    const float* __restrict__ wv,
    const float* __restrict__ bih, const float* __restrict__ bhh,
    int nht, int nwt)
{
  __shared__ double Al[32][132];
  __shared__ float  Bl[32][132];
  const int tid = threadIdx.x;
  const int r0 = blockIdx.x * 128;
  const int u0 = blockIdx.y * 32;
  const int tx = tid & 15, ty = tid >> 4;
  double acc[8][8];
  #pragma unroll
  for (int i=0;i<8;++i)
    #pragma unroll
    for (int j=0;j<8;++j) acc[i][j]=0.0;

  const int ra   = tid >> 1, kb16 = (tid & 1) * 16;
  const int cb   = ra;
  const int wrow = (cb >> 5)*HID + u0 + (cb & 31);

  for (int t = 0; t < nht + nwt; ++t){
    if (t < nht){
      int k0 = t*32;
      const double* s0 = hin + (size_t)(r0+ra)*HID + k0 + kb16;
      #pragma unroll
      for (int jj=0;jj<8;++jj){
        double2 v = *(const double2*)(s0 + 2*jj);
        Al[kb16+2*jj  ][ra] = v.x;
        Al[kb16+2*jj+1][ra] = v.y;
      }
      const float* s1 = Whh + (size_t)wrow*HID + k0 + kb16;
      #pragma unroll
      for (int jj=0;jj<4;++jj){
        float4 w = *(const float4*)(s1 + 4*jj);
        Bl[kb16+4*jj  ][cb] = w.x;
        Bl[kb16+4*jj+1][cb] = w.y;
        Bl[kb16+4*jj+2][cb] = w.z;
        Bl[kb16+4*jj+3][cb] = w.w;
      }
    } else {
      int k0 = (t - nht)*32;
      #pragma unroll
      for (int j=0;j<16;++j){
        int k = k0 + kb16 + j;
        Al[kb16+j][ra] = (k < WVD) ? (double)wv[(size_t)(r0+ra)*WVD + k] : 0.0;
        Bl[kb16+j][cb] = (k < WVD) ? Wih[(size_t)wrow*IND + EMB + k] : 0.f;
      }
    }
    __syncthreads();
    #pragma unroll
    for (int k=0;k<32;++k){
      double av[8], bv[8];
      #pragma unroll
      for (int i=0;i<8;++i) av[i] = Al[k][ty*8+i];
      #pragma unroll
      for (int j=0;j<8;++j) bv[j] = (double)Bl[k][tx + 16*j];
      #pragma unroll
      for (int i=0;i<8;++i)
        #pragma unroll
        for (int j=0;j<8;++j) acc[i][j] += av[i]*bv[j];
    }
    __syncthreads();
  }

  #pragma unroll
  for (int i=0;i<8;++i){
    int r = r0 + ty*8 + i;
    int tok = idx[r];
    const double* Er = E + (size_t)tok*G4;
    #pragma unroll
    for (int v=0;v<2;++v){
      int u = u0 + tx + 16*v;
      double pre[4];
      if (base){
        const double* Br = base + (size_t)r*G4;
        #pragma unroll
        for (int g=0;g<4;++g) pre[g] = acc[i][2*g+v] + Er[g*HID+u] + Br[g*HID+u];
      } else {
        #pragma unroll
        for (int g=0;g<4;++g) pre[g] = acc[i][2*g+v] + Er[g*HID+u]
                                     + (double)bih[g*HID+u] + (double)bhh[g*HID+u];
      }
      double co = cst[(size_t)r*HID + u];
      double cn = dsig(pre[1])*co + dsig(pre[0])*dtanh_(pre[2]);
      double hn = dsig(pre[3])*dtanh_(cn);
      cst[(size_t)r*HID + u]  = cn;
      hout[(size_t)r*HID + u] = hn;
    }
  }
}

__global__ __launch_bounds__(256) void logits_v3(
    const double* __restrict__ h, const float* __restrict__ Wlin,
    double* __restrict__ lbuf)
{
  __shared__ double Al[32][68];
  __shared__ float  Bl[32][68];
  const int tid = threadIdx.x;
  const int r0 = blockIdx.x*64, n0 = blockIdx.y*64, kk = blockIdx.z;
  const int kt0 = kk*11;
  const int kt1 = (kk==2) ? 32 : kt0 + 11;
  const int tx = tid & 15, ty = tid >> 4;
  double acc[4][4];
  #pragma unroll
  for (int i=0;i<4;++i)
    #pragma unroll
    for (int j=0;j<4;++j) acc[i][j]=0.0;

  const int ra = tid >> 2, kb8 = (tid & 3) * 8;
  const int wr = n0 + ra;
  const bool wok = (wr < VOC);
  for (int t = kt0; t < kt1; ++t){
    int k0 = t*32;
    const double* s0 = h + (size_t)(r0+ra)*HID + k0 + kb8;
    #pragma unroll
    for (int jj=0;jj<4;++jj){
      double2 v = *(const double2*)(s0 + 2*jj);
      Al[kb8+2*jj  ][ra] = v.x;
      Al[kb8+2*jj+1][ra] = v.y;
    }
    if (wok){
      const float* s1 = Wlin + (size_t)wr*HID + k0 + kb8;
      float4 w0 = *(const float4*)(s1+0);
      float4 w1 = *(const float4*)(s1+4);
      Bl[kb8+0][ra] = w0.x; Bl[kb8+1][ra] = w0.y;
      Bl[kb8+2][ra] = w0.z; Bl[kb8+3][ra] = w0.w;
      Bl[kb8+4][ra] = w1.x; Bl[kb8+5][ra] = w1.y;
      Bl[kb8+6][ra] = w1.z; Bl[kb8+7][ra] = w1.w;
    } else {
      #pragma unroll
      for (int j=0;j<8;++j) Bl[kb8+j][ra] = 0.f;
    }
    __syncthreads();
    #pragma unroll
    for (int k=0;k<32;++k){
      double av[4], bv[4];
      #pragma unroll
      for (int i=0;i<4;++i) av[i] = Al[k][ty*4+i];
      #pragma unroll
      for (int j=0;j<4;++j) bv[j] = (double)Bl[k][tx+16*j];
      #pragma unroll
      for (int i=0;i<4;++i)
        #pragma unroll
        for (int j=0;j<4;++j) acc[i][j] += av[i]*bv[j];
    }
    __syncthreads();
  }
  #pragma unroll
  for (int i=0;i<4;++i){
    int r = r0 + ty*4 + i;
    #pragma unroll
    for (int j=0;j<4;++j){
      int n = n0 + tx + 16*j;
      lbuf[(size_t)r*HID + kk*320 + n] = acc[i][j];
    }
  }
}

__global__ __launch_bounds__(256) void argmax_sk(
    const double* __restrict__ lbuf, const float* __restrict__ blin,
    int* __restrict__ idx, float* __restrict__ outp, float* __restrict__ outi)
{
  const int tid = threadIdx.x;
  const int r = blockIdx.x*4 + (tid >> 6);
  const int lane = tid & 63;
  const double* lr = lbuf + (size_t)r*HID;
  double v[5];
  double m = -INFINITY; int am = 0;
  #pragma unroll
  for (int t=0;t<5;++t){
    int col = lane + 64*t;
    if (col < VOC){
      double x = ((lr[col] + lr[320+col]) + lr[640+col]) + (double)blin[col];
      v[t] = x;
      if (x > m){ m = x; am = col; }
    } else v[t] = -INFINITY;
  }
  #pragma unroll
  for (int d=1; d<64; d<<=1){
    double om = __shfl_xor(m, d, 64);
    int   oa = __shfl_xor(am, d, 64);
    if (om > m || (om == m && oa < am)){ m = om; am = oa; }
  }
  double s = 0.0;
  #pragma unroll
  for (int t=0;t<5;++t){
    int col = lane + 64*t;
    if (col < VOC) s += exp(v[t] - m);
  }
  #pragma unroll
  for (int d=1; d<64; d<<=1) s += __shfl_xor(s, d, 64);
  if (lane == 0){
    idx[r]  = am;
    outp[r] = (float)(1.0/s);
    outi[r] = (float)am;
  }
}

// ======================= launch =======================

extern "C" void kernel_launch(void* const* d_in, const int* in_sizes, int n_in,
                              void* d_out, int out_size, void* d_ws, size_t ws_size,
                              hipStream_t stream){
  const float* wv   = (const float*)d_in[0];
  const float* emb  = (const float*)d_in[1];
  const float* Wih  = (const float*)d_in[2];
  const float* Whh  = (const float*)d_in[3];
  const float* bih  = (const float*)d_in[4];
  const float* bhh  = (const float*)d_in[5];
  const float* Wlin = (const float*)d_in[6];
  const float* blin = (const float*)d_in[7];
  float* out = (float*)d_out;

  char* w = (char*)d_ws;
  size_t off = 0;
  auto al = [](size_t b){ return (b + 255) & ~(size_t)255; };
  auto alloc = [&](size_t bytes) -> void* {
    void* p = w + off; off += al(bytes); return p;
  };

  const size_t fixed = al((size_t)VOC*G4*8) + al((size_t)BS*4);

  // tier selection: mode 2 = i8 MFMA (needs base+slices), 1 = f64+base, 0 = f64 no-base
  int R = 0; int mode = 0;
  for (int r = 4096; r >= 2048; r >>= 1){
    size_t need = fixed + 3*al((size_t)r*HID*8) + al((size_t)r*G4*8)
                + al((size_t)6*r*HID) + al((size_t)5*WPLANE) + al((size_t)5*VLPLANE);
    if (need <= ws_size){ R = r; mode = 2; break; }
  }
  if (!R){
    for (int r = 4096; r >= 1024; r >>= 1){
      if (fixed + 3*al((size_t)r*HID*8) + al((size_t)r*G4*8) <= ws_size){ R = r; mode = 1; break; }
    }
  }
  if (!R){
    for (int r = 8192; r >= 256; r >>= 1){
      if (fixed + 3*al((size_t)r*HID*8) <= ws_size){ R = r; mode = 0; break; }
    }
  }
  if (!R) return;

  double* Ed  = (double*)alloc((size_t)VOC*G4*8);
  int*    idx = (int*)   alloc((size_t)BS*4);
  double* h0  = (double*)alloc((size_t)R*HID*8);
  double* h1  = (double*)alloc((size_t)R*HID*8);
  double* cd  = (double*)alloc((size_t)R*HID*8);
  double* base = (mode >= 1) ? (double*)alloc((size_t)R*G4*8) : nullptr;
  signed char* hs  = (mode == 2) ? (signed char*)alloc((size_t)6*R*HID) : nullptr;
  signed char* wsl = (mode == 2) ? (signed char*)alloc((size_t)5*WPLANE) : nullptr;
  signed char* wvl = (mode == 2) ? (signed char*)alloc((size_t)5*VLPLANE) : nullptr;

  hipMemsetAsync(idx, 0, (size_t)BS*4, stream);
  ekernel_f64<<<dim3(16,17),256,0,stream>>>(emb, Wih, Ed);
  if (mode == 2){
    wslice<<<WPLANE/1024,256,0,stream>>>(Whh, wsl, WPLANE);
    hipMemsetAsync(wvl, 0, (size_t)5*VLPLANE, stream);
    wslice<<<(VOC*HID)/1024,256,0,stream>>>(Wlin, wvl, VLPLANE);
  }

  const int hplane = R*HID;
  for (int c0 = 0; c0 < BS; c0 += R){
    if (mode >= 1)
      base_v3<<<dim3(R/128, 32),256,0,stream>>>(wv + (size_t)c0*WVD, Wih, bih, bhh, base);
    hipMemsetAsync(cd, 0, (size_t)R*HID*8, stream);
    double* hb[2] = {h0, h1};
    for (int s = 0; s < NST; ++s){
      if (mode == 2){
        gates_i8<<<dim3(R/64, 64),256,0,stream>>>(
            hs, wsl, hb[(s+1)&1], cd, idx + c0, Ed, base,
            (s==0) ? 0 : HID/64, hplane, R/64);
        slice_h<<<R/2,256,0,stream>>>(hb[(s+1)&1], hs, hplane);
        logits_i8<<<dim3(R/64, VOCP/16),256,0,stream>>>(
            hs, wvl, hb[s&1], hplane);
        argmax_di<<<R/4,256,0,stream>>>(
            hb[s&1], blin, idx + c0,
            out + (size_t)s*BS + c0, out + (size_t)NST*BS + (size_t)s*BS + c0);
      } else {
        gates_v3<<<dim3(R/128, 32),256,0,stream>>>(
            hb[s&1], hb[(s+1)&1], cd, idx + c0, Ed, base,
            Whh, Wih, wv + (size_t)c0*WVD, bih, bhh,
            (s==0) ? 0 : HID/32, (mode==1) ? 0 : 10);
        logits_v3<<<dim3(R/64, 5, 3),256,0,stream>>>(
            hb[(s+1)&1], Wlin, hb[s&1]);
        argmax_sk<<<R/4,256,0,stream>>>(
            hb[s&1], blin, idx + c0,
            out + (size_t)s*BS + c0, out + (size_t)NST*BS + (size_t)s*BS + c0);
      }
    }
  }
}

// Round 10
// 24273.508 us; speedup vs baseline: 2.3175x; 2.1325x over previous
//
#include <hip/hip_runtime.h>
#include <math.h>

#define BS   16384
#define HID  1024
#define G4   4096
#define EMB  512
#define WVD  300
#define IND  812
#define VOC  258
#define NST  14
#define WPLANE 4194304            /* 4096*1024 */
#define VOCP 272
#define VLPLANE (VOCP*1024)

typedef int i32x4 __attribute__((ext_vector_type(4)));

#define MFMA8(d, sa, sb) asm("v_mfma_i32_16x16x64_i8 %0, %1, %2, %0" : "+v"(d) : "v"(sa), "v"(sb))

__device__ __forceinline__ double dsig(double x){ return 1.0/(1.0+exp(-x)); }
__device__ __forceinline__ double dtanh_(double x){
  double ax = fabs(x);
  double e = exp(-2.0*ax);
  double t = (1.0-e)/(1.0+e);
  return x < 0.0 ? -t : t;
}

// ---------------- E = emb @ W_ih[:, :512].T -> f64 [VOC][G4] ----------------
#define ETT 16
__global__ __launch_bounds__(256) void ekernel_f64(const float* __restrict__ emb,
                                                   const float* __restrict__ Wih,
                                                   double* __restrict__ E){
  __shared__ float elds[ETT][EMB];
  const int tid = threadIdx.x;
  const int n  = blockIdx.x*256 + tid;
  const int t0 = blockIdx.y*ETT;
  #pragma unroll
  for (int i = 0; i < 8; ++i){
    int fi = tid + 256*i;
    int tt = fi >> 7;
    int kk = (fi & 127) << 2;
    float4 v = make_float4(0.f,0.f,0.f,0.f);
    if (t0+tt < VOC) v = *(const float4*)(emb + (size_t)(t0+tt)*EMB + kk);
    *(float4*)&elds[tt][kk] = v;
  }
  __syncthreads();
  double acc[ETT];
  #pragma unroll
  for (int tt=0;tt<ETT;++tt) acc[tt]=0.0;
  const float* wr = Wih + (size_t)n*IND;
  for (int k=0;k<EMB;k+=4){
    float4 w = *(const float4*)(wr + k);
    double w0=w.x, w1=w.y, w2=w.z, w3=w.w;
    #pragma unroll
    for (int tt=0;tt<ETT;++tt){
      float4 e = *(const float4*)&elds[tt][k];
      acc[tt] += (double)e.x*w0 + (double)e.y*w1 + (double)e.z*w2 + (double)e.w*w3;
    }
  }
  #pragma unroll
  for (int tt=0;tt<ETT;++tt){
    int t = t0+tt;
    if (t < VOC) E[(size_t)t*G4 + n] = acc[tt];
  }
}

// ---------------- base = wv @ Wih[:,512:].T + b_ih + b_hh -> f64 [R][G4] ----------------
__global__ __launch_bounds__(256) void base_v3(const float* __restrict__ wv,
                                               const float* __restrict__ Wih,
                                               const float* __restrict__ bih,
                                               const float* __restrict__ bhh,
                                               double* __restrict__ base){
  __shared__ float Al[32][132];
  __shared__ float Bl[32][132];
  const int tid = threadIdx.x;
  const int r0 = blockIdx.x*128, n0 = blockIdx.y*128;
  const int tx = tid & 15, ty = tid >> 4;
  double acc[8][8];
  #pragma unroll
  for (int i=0;i<8;++i)
    #pragma unroll
    for (int j=0;j<8;++j) acc[i][j]=0.0;

  const int ra = tid >> 1, kb16 = (tid & 1) * 16;
  for (int t = 0; t < 10; ++t){
    int k0 = t*32;
    #pragma unroll
    for (int j=0;j<16;++j){
      int k = k0 + kb16 + j;
      Al[kb16+j][ra] = (k < WVD) ? wv[(size_t)(r0+ra)*WVD + k] : 0.f;
      Bl[kb16+j][ra] = (k < WVD) ? Wih[(size_t)(n0+ra)*IND + EMB + k] : 0.f;
    }
    __syncthreads();
    #pragma unroll
    for (int k=0;k<32;++k){
      double av[8], bv[8];
      #pragma unroll
      for (int i=0;i<8;++i) av[i] = (double)Al[k][ty*8+i];
      #pragma unroll
      for (int j=0;j<8;++j) bv[j] = (double)Bl[k][tx + 16*j];
      #pragma unroll
      for (int i=0;i<8;++i)
        #pragma unroll
        for (int j=0;j<8;++j) acc[i][j] += av[i]*bv[j];
    }
    __syncthreads();
  }
  #pragma unroll
  for (int i=0;i<8;++i){
    int r = r0 + ty*8 + i;
    #pragma unroll
    for (int j=0;j<8;++j){
      int n = n0 + tx + 16*j;
      base[(size_t)r*G4 + n] = acc[i][j] + (double)bih[n] + (double)bhh[n];
    }
  }
}

// ---------------- W slices: f32 -> 5 signed base-256 digit planes (exact, scale 2^40) ----------
__global__ __launch_bounds__(256) void wslice(const float* __restrict__ W,
                                              signed char* __restrict__ out, int plane){
  const int flat = (blockIdx.x*256 + threadIdx.x)*4;
  float4 w = *(const float4*)(W + flat);
  float we[4] = {w.x, w.y, w.z, w.w};
  unsigned int pack[5] = {0,0,0,0,0};
  #pragma unroll
  for (int e=0;e<4;++e){
    long long n = __double2ll_rn((double)we[e] * 1099511627776.0);  // 2^40
    #pragma unroll
    for (int s=4;s>=1;--s){
      int d = (int)(((n + 128) & 255) - 128);
      pack[s] |= ((unsigned int)(unsigned char)d) << (8*e);
      n = (n - d) >> 8;
    }
    pack[0] |= ((unsigned int)(unsigned char)(int)n) << (8*e);
  }
  #pragma unroll
  for (int s=0;s<5;++s)
    *(unsigned int*)(out + (size_t)s*plane + flat) = pack[s];
}

// ---------------- h slices: f64 -> 6 signed base-256 digit planes (scale 2^46) ----------------
__global__ __launch_bounds__(256) void slice_h(const double* __restrict__ h,
                                               signed char* __restrict__ hs, int hplane){
  const long long flat = ((long long)blockIdx.x*256 + threadIdx.x)*8;
  double v[8];
  #pragma unroll
  for (int q=0;q<4;++q)
    *(double2*)&v[2*q] = *(const double2*)(h + flat + 2*q);
  unsigned long long pack[6] = {0,0,0,0,0,0};
  #pragma unroll
  for (int e=0;e<8;++e){
    long long n = __double2ll_rn(v[e] * 70368744177664.0);   // 2^46
    #pragma unroll
    for (int s=5;s>=1;--s){
      int d = (int)(((n + 128) & 255) - 128);
      pack[s] |= ((unsigned long long)(unsigned char)d) << (8*e);
      n = (n - d) >> 8;
    }
    pack[0] |= ((unsigned long long)(unsigned char)(int)n) << (8*e);
  }
  #pragma unroll
  for (int s=0;s<6;++s)
    *(unsigned long long*)(hs + (size_t)s*hplane + flat) = pack[s];
}

// all digit pairs i+j<=5 (20) -- logits
#define MFMA20(ACC) \
    MFMA8(ACC[0], a[0], b[0]); \
    MFMA8(ACC[1], a[0], b[1]); \
    MFMA8(ACC[2], a[0], b[2]); \
    MFMA8(ACC[3], a[0], b[3]); \
    MFMA8(ACC[4], a[0], b[4]); \
    MFMA8(ACC[1], a[1], b[0]); \
    MFMA8(ACC[2], a[1], b[1]); \
    MFMA8(ACC[3], a[1], b[2]); \
    MFMA8(ACC[4], a[1], b[3]); \
    MFMA8(ACC[5], a[1], b[4]); \
    MFMA8(ACC[2], a[2], b[0]); \
    MFMA8(ACC[3], a[2], b[1]); \
    MFMA8(ACC[4], a[2], b[2]); \
    MFMA8(ACC[5], a[2], b[3]); \
    MFMA8(ACC[3], a[3], b[0]); \
    MFMA8(ACC[4], a[3], b[1]); \
    MFMA8(ACC[5], a[3], b[2]); \
    MFMA8(ACC[4], a[4], b[0]); \
    MFMA8(ACC[5], a[4], b[1]); \
    MFMA8(ACC[5], a[5], b[0]);

// digit pairs i+j<=4 (15) -- gates (dropped s=5 terms: <5e-9 worst-case)
#define MFMA15(ACC) \
    MFMA8(ACC[0], a[0], b[0]); \
    MFMA8(ACC[1], a[0], b[1]); \
    MFMA8(ACC[2], a[0], b[2]); \
    MFMA8(ACC[3], a[0], b[3]); \
    MFMA8(ACC[4], a[0], b[4]); \
    MFMA8(ACC[1], a[1], b[0]); \
    MFMA8(ACC[2], a[1], b[1]); \
    MFMA8(ACC[3], a[1], b[2]); \
    MFMA8(ACC[4], a[1], b[3]); \
    MFMA8(ACC[2], a[2], b[0]); \
    MFMA8(ACC[3], a[2], b[1]); \
    MFMA8(ACC[4], a[2], b[2]); \
    MFMA8(ACC[3], a[3], b[0]); \
    MFMA8(ACC[4], a[3], b[1]); \
    MFMA8(ACC[4], a[4], b[0]);

// ---------------- gates via i8 MFMA, LDS-double-buffered B + in-register LSTM cell ------------
__global__ __launch_bounds__(256) void gates_i8(
    const signed char* __restrict__ hs, const signed char* __restrict__ wsl,
    double* __restrict__ hout, double* __restrict__ cst,
    const int* __restrict__ idx, const double* __restrict__ E,
    const double* __restrict__ base, int nht, int hplane, int nbx)
{
  __shared__ __align__(16) signed char Bl[40960];   // 2 x 20KB double buffer
  const int tid = threadIdx.x;
  const int lane = tid & 63, wid = tid >> 6;
  const int l15 = lane & 15, l4 = lane >> 4;
  // supertile swizzle: 8 u-blocks per group -> B planes L2-resident
  const int f = blockIdx.x + nbx*blockIdx.y;
  const int G = nbx*8;
  const int grp = f / G, wi = f - grp*G;
  const int lbx = wi % nbx, lby = grp*8 + wi/nbx;
  const int r0 = lbx*64, u0 = lby*16;

  i32x4 acc[4][5];
  #pragma unroll
  for (int nt=0;nt<4;++nt)
    #pragma unroll
    for (int s=0;s<5;++s) acc[nt][s] = (i32x4)(0);
  asm volatile("s_nop 3" ::);   // VALU-write -> MFMA SrcC hazard guard

  const int aoff = (r0 + wid*16 + l15)*1024 + l4*16;
  // staging: round r stages digit-plane r; thread tid covers (gate=wid, unit=lane>>2, kq=lane&3)
  const size_t soff = ((size_t)wid*HID + u0 + (lane >> 2))*1024 + (lane & 3)*16;
  const int dst0 = tid*16;

  if (nht > 0){
    {
      i32x4 sreg[5];
      #pragma unroll
      for (int r=0;r<5;++r)
        sreg[r] = *(const i32x4*)(wsl + soff + (size_t)r*WPLANE);
      #pragma unroll
      for (int r=0;r<5;++r)
        *(i32x4*)(Bl + r*4096 + dst0) = sreg[r];
    }
    __syncthreads();

    for (int t = 0; t < nht; ++t){
      const int cur = (t & 1)*20480;
      const int nxt = ((t+1) & 1)*20480;
      i32x4 sreg[5];
      if (t+1 < nht){
        const size_t sk = soff + (size_t)(t+1)*64;
        #pragma unroll
        for (int r=0;r<5;++r)
          sreg[r] = *(const i32x4*)(wsl + sk + (size_t)r*WPLANE);
      }
      i32x4 a[5];
      #pragma unroll
      for (int i=0;i<5;++i)
        a[i] = *(const i32x4*)(hs + aoff + (size_t)i*hplane + t*64);
      #pragma unroll
      for (int nt=0;nt<4;++nt){
        const int boff = cur + nt*1024 + l15*64 + l4*16;
        i32x4 b[5];
        #pragma unroll
        for (int j=0;j<5;++j)
          b[j] = *(const i32x4*)(Bl + boff + j*4096);
        MFMA15(acc[nt]);
      }
      if (t+1 < nht){
        #pragma unroll
        for (int r=0;r<5;++r)
          *(i32x4*)(Bl + nxt + r*4096 + dst0) = sreg[r];
        __syncthreads();
      }
    }
  }
  asm volatile("s_nop 7\ns_nop 7\ns_nop 7" ::);  // MFMA -> VALU read hazard guard

  double val[4][4];
  #pragma unroll
  for (int nt=0;nt<4;++nt){
    #pragma unroll
    for (int e=0;e<4;++e){
      double v = (double)acc[nt][4][e];
      v = v*0.00390625 + (double)acc[nt][3][e];
      v = v*0.00390625 + (double)acc[nt][2][e];
      v = v*0.00390625 + (double)acc[nt][1][e];
      v = v*0.00390625 + (double)acc[nt][0][e];
      val[nt][e] = v * 6.103515625e-05;   // 2^-14
    }
  }
  const int u = u0 + l15;
  #pragma unroll
  for (int e=0;e<4;++e){
    const int r = r0 + wid*16 + l4*4 + e;
    const int tok = idx[r];
    const double* Er = E + (size_t)tok*G4;
    const double* Br = base + (size_t)r*G4;
    double pre[4];
    #pragma unroll
    for (int g=0;g<4;++g) pre[g] = val[g][e] + Er[g*HID+u] + Br[g*HID+u];
    double co = cst[(size_t)r*HID + u];
    double cn = dsig(pre[1])*co + dsig(pre[0])*dtanh_(pre[2]);
    double hn = dsig(pre[3])*dtanh_(cn);
    cst[(size_t)r*HID + u]  = cn;
    hout[(size_t)r*HID + u] = hn;
  }
}

// ---------------- logits via i8 MFMA: lbuf[r][n] = (Wlin . h)  (no bias) ----------------
__global__ __launch_bounds__(256) void logits_i8(
    const signed char* __restrict__ hs, const signed char* __restrict__ wvl,
    double* __restrict__ lbuf, int hplane)
{
  const int tid = threadIdx.x;
  const int lane = tid & 63, wid = tid >> 6;
  const int l15 = lane & 15, l4 = lane >> 4;
  const int r0 = blockIdx.x*64, n0 = blockIdx.y*16;

  i32x4 acc[6];
  #pragma unroll
  for (int s=0;s<6;++s) acc[s] = (i32x4)(0);
  asm volatile("s_nop 3" ::);

  const int aoff = (r0 + wid*16 + l15)*1024 + l4*16;
  const int boff0 = (n0 + l15)*1024 + l4*16;

  for (int t = 0; t < 16; ++t){
    const int k0 = t*64;
    i32x4 a[6], b[5];
    #pragma unroll
    for (int i=0;i<6;++i)
      a[i] = *(const i32x4*)(hs + aoff + i*hplane + k0);
    #pragma unroll
    for (int j=0;j<5;++j)
      b[j] = *(const i32x4*)(wvl + boff0 + j*VLPLANE + k0);
    MFMA20(acc);
  }
  asm volatile("s_nop 7\ns_nop 7\ns_nop 7" ::);

  #pragma unroll
  for (int e=0;e<4;++e){
    double v = (double)acc[5][e];
    v = v*0.00390625 + (double)acc[4][e];
    v = v*0.00390625 + (double)acc[3][e];
    v = v*0.00390625 + (double)acc[2][e];
    v = v*0.00390625 + (double)acc[1][e];
    v = v*0.00390625 + (double)acc[0][e];
    v *= 6.103515625e-05;
    const int r = r0 + wid*16 + l4*4 + e;
    lbuf[(size_t)r*HID + n0 + l15] = v;
  }
}

// ---------------- direct argmax ----------------
__global__ __launch_bounds__(256) void argmax_di(
    const double* __restrict__ lbuf, const float* __restrict__ blin,
    int* __restrict__ idx, float* __restrict__ outp, float* __restrict__ outi)
{
  const int tid = threadIdx.x;
  const int r = blockIdx.x*4 + (tid >> 6);
  const int lane = tid & 63;
  const double* lr = lbuf + (size_t)r*HID;
  double v[5];
  double m = -INFINITY; int am = 0;
  #pragma unroll
  for (int t=0;t<5;++t){
    int col = lane + 64*t;
    if (col < VOC){
      double x = lr[col] + (double)blin[col];
      v[t] = x;
      if (x > m){ m = x; am = col; }
    } else v[t] = -INFINITY;
  }
  #pragma unroll
  for (int d=1; d<64; d<<=1){
    double om = __shfl_xor(m, d, 64);
    int   oa = __shfl_xor(am, d, 64);
    if (om > m || (om == m && oa < am)){ m = om; am = oa; }
  }
  double s = 0.0;
  #pragma unroll
  for (int t=0;t<5;++t){
    int col = lane + 64*t;
    if (col < VOC) s += exp(v[t] - m);
  }
  #pragma unroll
  for (int d=1; d<64; d<<=1) s += __shfl_xor(s, d, 64);
  if (lane == 0){
    idx[r]  = am;
    outp[r] = (float)(1.0/s);
    outi[r] = (float)am;
  }
}

// ================= f64 fallback kernels =================

__global__ __launch_bounds__(256) void gates_v3(
    const double* __restrict__ hin, double* __restrict__ hout,
    double* __restrict__ cst, const int* __restrict__ idx,
    const double* __restrict__ E, const double* __restrict__ base,
    const float* __restrict__ Whh, const float* __restrict__ Wih,
    const float* __restrict__ wv,
    const float* __restrict__ bih, const float* __restrict__ bhh,
    int nht, int nwt)
{
  __shared__ double Al[32][132];
  __shared__ float  Bl[32][132];
  const int tid = threadIdx.x;
  const int r0 = blockIdx.x * 128;
  const int u0 = blockIdx.y * 32;
  const int tx = tid & 15, ty = tid >> 4;
  double acc[8][8];
  #pragma unroll
  for (int i=0;i<8;++i)
    #pragma unroll
    for (int j=0;j<8;++j) acc[i][j]=0.0;

  const int ra   = tid >> 1, kb16 = (tid & 1) * 16;
  const int cb   = ra;
  const int wrow = (cb >> 5)*HID + u0 + (cb & 31);

  for (int t = 0; t < nht + nwt; ++t){
    if (t < nht){
      int k0 = t*32;
      const double* s0 = hin + (size_t)(r0+ra)*HID + k0 + kb16;
      #pragma unroll
      for (int jj=0;jj<8;++jj){
        double2 v = *(const double2*)(s0 + 2*jj);
        Al[kb16+2*jj  ][ra] = v.x;
        Al[kb16+2*jj+1][ra] = v.y;
      }
      const float* s1 = Whh + (size_t)wrow*HID + k0 + kb16;
      #pragma unroll
      for (int jj=0;jj<4;++jj){
        float4 w = *(const float4*)(s1 + 4*jj);
        Bl[kb16+4*jj  ][cb] = w.x;
        Bl[kb16+4*jj+1][cb] = w.y;
        Bl[kb16+4*jj+2][cb] = w.z;
        Bl[kb16+4*jj+3][cb] = w.w;
      }
    } else {
      int k0 = (t - nht)*32;
      #pragma unroll
      for (int j=0;j<16;++j){
        int k = k0 + kb16 + j;
        Al[kb16+j][ra] = (k < WVD) ? (double)wv[(size_t)(r0+ra)*WVD + k] : 0.0;
        Bl[kb16+j][cb] = (k < WVD) ? Wih[(size_t)wrow*IND + EMB + k] : 0.f;
      }
    }
    __syncthreads();
    #pragma unroll
    for (int k=0;k<32;++k){
      double av[8], bv[8];
      #pragma unroll
      for (int i=0;i<8;++i) av[i] = Al[k][ty*8+i];
      #pragma unroll
      for (int j=0;j<8;++j) bv[j] = (double)Bl[k][tx + 16*j];
      #pragma unroll
      for (int i=0;i<8;++i)
        #pragma unroll
        for (int j=0;j<8;++j) acc[i][j] += av[i]*bv[j];
    }
    __syncthreads();
  }

  #pragma unroll
  for (int i=0;i<8;++i){
    int r = r0 + ty*8 + i;
    int tok = idx[r];
    const double* Er = E + (size_t)tok*G4;
    #pragma unroll
    for (int v=0;v<2;++v){
      int u = u0 + tx + 16*v;
      double pre[4];
      if (base){
        const double* Br = base + (size_t)r*G4;
        #pragma unroll
        for (int g=0;g<4;++g) pre[g] = acc[i][2*g+v] + Er[g*HID+u] + Br[g*HID+u];
      } else {
        #pragma unroll
        for (int g=0;g<4;++g) pre[g] = acc[i][2*g+v] + Er[g*HID+u]
                                     + (double)bih[g*HID+u] + (double)bhh[g*HID+u];
      }
      double co = cst[(size_t)r*HID + u];
      double cn = dsig(pre[1])*co + dsig(pre[0])*dtanh_(pre[2]);
      double hn = dsig(pre[3])*dtanh_(cn);
      cst[(size_t)r*HID + u]  = cn;
      hout[(size_t)r*HID + u] = hn;
    }
  }
}

__global__ __launch_bounds__(256) void logits_v3(
    const double* __restrict__ h, const float* __restrict__ Wlin,
    double* __restrict__ lbuf)
{
  __shared__ double Al[32][68];
  __shared__ float  Bl[32][68];
  const int tid = threadIdx.x;
  const int r0 = blockIdx.x*64, n0 = blockIdx.y*64, kk = blockIdx.z;
  const int kt0 = kk*11;
  const int kt1 = (kk==2) ? 32 : kt0 + 11;
  const int tx = tid & 15, ty = tid >> 4;
  double acc[4][4];
  #pragma unroll
  for (int i=0;i<4;++i)
    #pragma unroll
    for (int j=0;j<4;++j) acc[i][j]=0.0;

  const int ra = tid >> 2, kb8 = (tid & 3) * 8;
  const int wr = n0 + ra;
  const bool wok = (wr < VOC);
  for (int t = kt0; t < kt1; ++t){
    int k0 = t*32;
    const double* s0 = h + (size_t)(r0+ra)*HID + k0 + kb8;
    #pragma unroll
    for (int jj=0;jj<4;++jj){
      double2 v = *(const double2*)(s0 + 2*jj);
      Al[kb8+2*jj  ][ra] = v.x;
      Al[kb8+2*jj+1][ra] = v.y;
    }
    if (wok){
      const float* s1 = Wlin + (size_t)wr*HID + k0 + kb8;
      float4 w0 = *(const float4*)(s1+0);
      float4 w1 = *(const float4*)(s1+4);
      Bl[kb8+0][ra] = w0.x; Bl[kb8+1][ra] = w0.y;
      Bl[kb8+2][ra] = w0.z; Bl[kb8+3][ra] = w0.w;
      Bl[kb8+4][ra] = w1.x; Bl[kb8+5][ra] = w1.y;
      Bl[kb8+6][ra] = w1.z; Bl[kb8+7][ra] = w1.w;
    } else {
      #pragma unroll
      for (int j=0;j<8;++j) Bl[kb8+j][ra] = 0.f;
    }
    __syncthreads();
    #pragma unroll
    for (int k=0;k<32;++k){
      double av[4], bv[4];
      #pragma unroll
      for (int i=0;i<4;++i) av[i] = Al[k][ty*4+i];
      #pragma unroll
      for (int j=0;j<4;++j) bv[j] = (double)Bl[k][tx+16*j];
      #pragma unroll
      for (int i=0;i<4;++i)
        #pragma unroll
        for (int j=0;j<4;++j) acc[i][j] += av[i]*bv[j];
    }
    __syncthreads();
  }
  #pragma unroll
  for (int i=0;i<4;++i){
    int r = r0 + ty*4 + i;
    #pragma unroll
    for (int j=0;j<4;++j){
      int n = n0 + tx + 16*j;
      lbuf[(size_t)r*HID + kk*320 + n] = acc[i][j];
    }
  }
}

__global__ __launch_bounds__(256) void argmax_sk(
    const double* __restrict__ lbuf, const float* __restrict__ blin,
    int* __restrict__ idx, float* __restrict__ outp, float* __restrict__ outi)
{
  const int tid = threadIdx.x;
  const int r = blockIdx.x*4 + (tid >> 6);
  const int lane = tid & 63;
  const double* lr = lbuf + (size_t)r*HID;
  double v[5];
  double m = -INFINITY; int am = 0;
  #pragma unroll
  for (int t=0;t<5;++t){
    int col = lane + 64*t;
    if (col < VOC){
      double x = ((lr[col] + lr[320+col]) + lr[640+col]) + (double)blin[col];
      v[t] = x;
      if (x > m){ m = x; am = col; }
    } else v[t] = -INFINITY;
  }
  #pragma unroll
  for (int d=1; d<64; d<<=1){
    double om = __shfl_xor(m, d, 64);
    int   oa = __shfl_xor(am, d, 64);
    if (om > m || (om == m && oa < am)){ m = om; am = oa; }
  }
  double s = 0.0;
  #pragma unroll
  for (int t=0;t<5;++t){
    int col = lane + 64*t;
    if (col < VOC) s += exp(v[t] - m);
  }
  #pragma unroll
  for (int d=1; d<64; d<<=1) s += __shfl_xor(s, d, 64);
  if (lane == 0){
    idx[r]  = am;
    outp[r] = (float)(1.0/s);
    outi[r] = (float)am;
  }
}

// ======================= launch =======================

extern "C" void kernel_launch(void* const* d_in, const int* in_sizes, int n_in,
                              void* d_out, int out_size, void* d_ws, size_t ws_size,
                              hipStream_t stream){
  const float* wv   = (const float*)d_in[0];
  const float* emb  = (const float*)d_in[1];
  const float* Wih  = (const float*)d_in[2];
  const float* Whh  = (const float*)d_in[3];
  const float* bih  = (const float*)d_in[4];
  const float* bhh  = (const float*)d_in[5];
  const float* Wlin = (const float*)d_in[6];
  const float* blin = (const float*)d_in[7];
  float* out = (float*)d_out;

  char* w = (char*)d_ws;
  size_t off = 0;
  auto al = [](size_t b){ return (b + 255) & ~(size_t)255; };
  auto alloc = [&](size_t bytes) -> void* {
    void* p = w + off; off += al(bytes); return p;
  };

  const size_t fixed = al((size_t)VOC*G4*8) + al((size_t)BS*4);

  int R = 0; int mode = 0;
  for (int r = 4096; r >= 2048; r >>= 1){
    size_t need = fixed + 3*al((size_t)r*HID*8) + al((size_t)r*G4*8)
                + al((size_t)6*r*HID) + al((size_t)5*WPLANE) + al((size_t)5*VLPLANE);
    if (need <= ws_size){ R = r; mode = 2; break; }
  }
  if (!R){
    for (int r = 4096; r >= 1024; r >>= 1){
      if (fixed + 3*al((size_t)r*HID*8) + al((size_t)r*G4*8) <= ws_size){ R = r; mode = 1; break; }
    }
  }
  if (!R){
    for (int r = 8192; r >= 256; r >>= 1){
      if (fixed + 3*al((size_t)r*HID*8) <= ws_size){ R = r; mode = 0; break; }
    }
  }
  if (!R) return;

  double* Ed  = (double*)alloc((size_t)VOC*G4*8);
  int*    idx = (int*)   alloc((size_t)BS*4);
  double* h0  = (double*)alloc((size_t)R*HID*8);
  double* h1  = (double*)alloc((size_t)R*HID*8);
  double* cd  = (double*)alloc((size_t)R*HID*8);
  double* base = (mode >= 1) ? (double*)alloc((size_t)R*G4*8) : nullptr;
  signed char* hs  = (mode == 2) ? (signed char*)alloc((size_t)6*R*HID) : nullptr;
  signed char* wsl = (mode == 2) ? (signed char*)alloc((size_t)5*WPLANE) : nullptr;
  signed char* wvl = (mode == 2) ? (signed char*)alloc((size_t)5*VLPLANE) : nullptr;

  hipMemsetAsync(idx, 0, (size_t)BS*4, stream);
  ekernel_f64<<<dim3(16,17),256,0,stream>>>(emb, Wih, Ed);
  if (mode == 2){
    wslice<<<WPLANE/1024,256,0,stream>>>(Whh, wsl, WPLANE);
    hipMemsetAsync(wvl, 0, (size_t)5*VLPLANE, stream);
    wslice<<<(VOC*HID)/1024,256,0,stream>>>(Wlin, wvl, VLPLANE);
  }

  const int hplane = R*HID;
  for (int c0 = 0; c0 < BS; c0 += R){
    if (mode >= 1)
      base_v3<<<dim3(R/128, 32),256,0,stream>>>(wv + (size_t)c0*WVD, Wih, bih, bhh, base);
    hipMemsetAsync(cd, 0, (size_t)R*HID*8, stream);
    double* hb[2] = {h0, h1};
    for (int s = 0; s < NST; ++s){
      if (mode == 2){
        gates_i8<<<dim3(R/64, 64),256,0,stream>>>(
            hs, wsl, hb[(s+1)&1], cd, idx + c0, Ed, base,
            (s==0) ? 0 : HID/64, hplane, R/64);
        slice_h<<<R/2,256,0,stream>>>(hb[(s+1)&1], hs, hplane);
        logits_i8<<<dim3(R/64, VOCP/16),256,0,stream>>>(
            hs, wvl, hb[s&1], hplane);
        argmax_di<<<R/4,256,0,stream>>>(
            hb[s&1], blin, idx + c0,
            out + (size_t)s*BS + c0, out + (size_t)NST*BS + (size_t)s*BS + c0);
      } else {
        gates_v3<<<dim3(R/128, 32),256,0,stream>>>(
            hb[s&1], hb[(s+1)&1], cd, idx + c0, Ed, base,
            Whh, Wih, wv + (size_t)c0*WVD, bih, bhh,
            (s==0) ? 0 : HID/32, (mode==1) ? 0 : 10);
        logits_v3<<<dim3(R/64, 5, 3),256,0,stream>>>(
            hb[(s+1)&1], Wlin, hb[s&1]);
        argmax_sk<<<R/4,256,0,stream>>>(
            hb[s&1], blin, idx + c0,
            out + (size_t)s*BS + c0, out + (size_t)NST*BS + (size_t)s*BS + c0);
      }
    }
  }
}

// Round 11
// 22189.235 us; speedup vs baseline: 2.5352x; 1.0939x over previous
//
#include <hip/hip_runtime.h>
#include <math.h>

#define BS   16384
#define HID  1024
#define G4   4096
#define EMB  512
#define WVD  300
#define IND  812
#define VOC  258
#define NST  14
#define WPLANE 4194304            /* 4096*1024 */
#define VOCP 272
#define VLPLANE (VOCP*1024)

typedef int i32x4 __attribute__((ext_vector_type(4)));

#define MFMA8(d, sa, sb) asm("v_mfma_i32_16x16x64_i8 %0, %1, %2, %0" : "+v"(d) : "v"(sa), "v"(sb))

// digit pairs i+j<=4 (15) with explicit operand arrays
#define MFMA15AB(ACC, A, B) \
    MFMA8(ACC[0], A[0], B[0]); \
    MFMA8(ACC[1], A[0], B[1]); \
    MFMA8(ACC[2], A[0], B[2]); \
    MFMA8(ACC[3], A[0], B[3]); \
    MFMA8(ACC[4], A[0], B[4]); \
    MFMA8(ACC[1], A[1], B[0]); \
    MFMA8(ACC[2], A[1], B[1]); \
    MFMA8(ACC[3], A[1], B[2]); \
    MFMA8(ACC[4], A[1], B[3]); \
    MFMA8(ACC[2], A[2], B[0]); \
    MFMA8(ACC[3], A[2], B[1]); \
    MFMA8(ACC[4], A[2], B[2]); \
    MFMA8(ACC[3], A[3], B[0]); \
    MFMA8(ACC[4], A[3], B[1]); \
    MFMA8(ACC[4], A[4], B[0]);

#define GLL(src, dst) __builtin_amdgcn_global_load_lds( \
    (const __attribute__((address_space(1))) void*)(const void*)(src), \
    (__attribute__((address_space(3))) void*)(void*)(dst), 16, 0, 0)

__device__ __forceinline__ double dsig(double x){ return 1.0/(1.0+exp(-x)); }
__device__ __forceinline__ double dtanh_(double x){
  double ax = fabs(x);
  double e = exp(-2.0*ax);
  double t = (1.0-e)/(1.0+e);
  return x < 0.0 ? -t : t;
}

// ---------------- E = emb @ W_ih[:, :512].T -> f64 [VOC][G4] ----------------
#define ETT 16
__global__ __launch_bounds__(256) void ekernel_f64(const float* __restrict__ emb,
                                                   const float* __restrict__ Wih,
                                                   double* __restrict__ E){
  __shared__ float elds[ETT][EMB];
  const int tid = threadIdx.x;
  const int n  = blockIdx.x*256 + tid;
  const int t0 = blockIdx.y*ETT;
  #pragma unroll
  for (int i = 0; i < 8; ++i){
    int fi = tid + 256*i;
    int tt = fi >> 7;
    int kk = (fi & 127) << 2;
    float4 v = make_float4(0.f,0.f,0.f,0.f);
    if (t0+tt < VOC) v = *(const float4*)(emb + (size_t)(t0+tt)*EMB + kk);
    *(float4*)&elds[tt][kk] = v;
  }
  __syncthreads();
  double acc[ETT];
  #pragma unroll
  for (int tt=0;tt<ETT;++tt) acc[tt]=0.0;
  const float* wr = Wih + (size_t)n*IND;
  for (int k=0;k<EMB;k+=4){
    float4 w = *(const float4*)(wr + k);
    double w0=w.x, w1=w.y, w2=w.z, w3=w.w;
    #pragma unroll
    for (int tt=0;tt<ETT;++tt){
      float4 e = *(const float4*)&elds[tt][k];
      acc[tt] += (double)e.x*w0 + (double)e.y*w1 + (double)e.z*w2 + (double)e.w*w3;
    }
  }
  #pragma unroll
  for (int tt=0;tt<ETT;++tt){
    int t = t0+tt;
    if (t < VOC) E[(size_t)t*G4 + n] = acc[tt];
  }
}

// ---------------- base = wv @ Wih[:,512:].T + b_ih + b_hh -> f64 [R][G4] ----------------
__global__ __launch_bounds__(256) void base_v3(const float* __restrict__ wv,
                                               const float* __restrict__ Wih,
                                               const float* __restrict__ bih,
                                               const float* __restrict__ bhh,
                                               double* __restrict__ base){
  __shared__ float Al[32][132];
  __shared__ float Bl[32][132];
  const int tid = threadIdx.x;
  const int r0 = blockIdx.x*128, n0 = blockIdx.y*128;
  const int tx = tid & 15, ty = tid >> 4;
  double acc[8][8];
  #pragma unroll
  for (int i=0;i<8;++i)
    #pragma unroll
    for (int j=0;j<8;++j) acc[i][j]=0.0;

  const int ra = tid >> 1, kb16 = (tid & 1) * 16;
  for (int t = 0; t < 10; ++t){
    int k0 = t*32;
    #pragma unroll
    for (int j=0;j<16;++j){
      int k = k0 + kb16 + j;
      Al[kb16+j][ra] = (k < WVD) ? wv[(size_t)(r0+ra)*WVD + k] : 0.f;
      Bl[kb16+j][ra] = (k < WVD) ? Wih[(size_t)(n0+ra)*IND + EMB + k] : 0.f;
    }
    __syncthreads();
    #pragma unroll
    for (int k=0;k<32;++k){
      double av[8], bv[8];
      #pragma unroll
      for (int i=0;i<8;++i) av[i] = (double)Al[k][ty*8+i];
      #pragma unroll
      for (int j=0;j<8;++j) bv[j] = (double)Bl[k][tx + 16*j];
      #pragma unroll
      for (int i=0;i<8;++i)
        #pragma unroll
        for (int j=0;j<8;++j) acc[i][j] += av[i]*bv[j];
    }
    __syncthreads();
  }
  #pragma unroll
  for (int i=0;i<8;++i){
    int r = r0 + ty*8 + i;
    #pragma unroll
    for (int j=0;j<8;++j){
      int n = n0 + tx + 16*j;
      base[(size_t)r*G4 + n] = acc[i][j] + (double)bih[n] + (double)bhh[n];
    }
  }
}

// ---------------- W slices: f32 -> 5 signed base-256 digit planes (exact, scale 2^40) ----------
__global__ __launch_bounds__(256) void wslice(const float* __restrict__ W,
                                              signed char* __restrict__ out, int plane){
  const int flat = (blockIdx.x*256 + threadIdx.x)*4;
  float4 w = *(const float4*)(W + flat);
  float we[4] = {w.x, w.y, w.z, w.w};
  unsigned int pack[5] = {0,0,0,0,0};
  #pragma unroll
  for (int e=0;e<4;++e){
    long long n = __double2ll_rn((double)we[e] * 1099511627776.0);  // 2^40
    #pragma unroll
    for (int s=4;s>=1;--s){
      int d = (int)(((n + 128) & 255) - 128);
      pack[s] |= ((unsigned int)(unsigned char)d) << (8*e);
      n = (n - d) >> 8;
    }
    pack[0] |= ((unsigned int)(unsigned char)(int)n) << (8*e);
  }
  #pragma unroll
  for (int s=0;s<5;++s)
    *(unsigned int*)(out + (size_t)s*plane + flat) = pack[s];
}

// ---------------- h slices: f64 -> 5 signed base-256 digit planes (scale 2^38, pre-rounded) ----
__global__ __launch_bounds__(256) void slice_h(const double* __restrict__ h,
                                               signed char* __restrict__ hs, int hplane){
  const long long flat = ((long long)blockIdx.x*256 + threadIdx.x)*8;
  double v[8];
  #pragma unroll
  for (int q=0;q<4;++q)
    *(double2*)&v[2*q] = *(const double2*)(h + flat + 2*q);
  unsigned long long pack[5] = {0,0,0,0,0};
  #pragma unroll
  for (int e=0;e<8;++e){
    long long n = __double2ll_rn(v[e] * 70368744177664.0);   // 2^46
    long long m = (n + 128) >> 8;                             // round -> scale 2^38
    #pragma unroll
    for (int s=4;s>=1;--s){
      int d = (int)(((m + 128) & 255) - 128);
      pack[s] |= ((unsigned long long)(unsigned char)d) << (8*e);
      m = (m - d) >> 8;
    }
    pack[0] |= ((unsigned long long)(unsigned char)(int)m) << (8*e);
  }
  #pragma unroll
  for (int s=0;s<5;++s)
    *(unsigned long long*)(hs + (size_t)s*hplane + flat) = pack[s];
}

// ---------------- gates via i8 MFMA: 128 rows x 16 units, mt=2/wave, async-LDS B ---------------
// wave wid: rows r0+wid*32 .. +31 (2 m-tiles). wave's 4 n-tiles = the 4 GATES of units
// u0..u0+15 -> lane holds all 4 gates of its 8 (row,unit) cells: LSTM in-register.
// B staged via global_load_lds (wave-uniform dst + lane*16), double-buffered, 1 barrier/k-step.
__global__ __launch_bounds__(256) void gates_i8(
    const signed char* __restrict__ hs, const signed char* __restrict__ wsl,
    double* __restrict__ hout, double* __restrict__ cst,
    const int* __restrict__ idx, const double* __restrict__ E,
    const double* __restrict__ base, int nht, int hplane, int nbx)
{
  __shared__ __align__(16) signed char Bl[40960];   // 2 x 20KB double buffer
  const int tid = threadIdx.x;
  const int lane = tid & 63, wid = tid >> 6;
  const int l15 = lane & 15, l4 = lane >> 4;
  // supertile swizzle: 8 u-blocks per group -> B planes L2-resident
  const int f = blockIdx.x + nbx*blockIdx.y;
  const int G = nbx*8;
  const int grp = f / G, wi = f - grp*G;
  const int lbx = wi % nbx, lby = grp*8 + wi/nbx;
  const int r0 = lbx*128, u0 = lby*16;

  i32x4 acc[4][2][5];
  #pragma unroll
  for (int nt=0;nt<4;++nt)
    #pragma unroll
    for (int mt=0;mt<2;++mt)
      #pragma unroll
      for (int s=0;s<5;++s) acc[nt][mt][s] = (i32x4)(0);
  asm volatile("s_nop 3" ::);   // VALU-write -> MFMA SrcC hazard guard

  const int arow = r0 + wid*32;
  const int aoff0 = (arow      + l15)*1024 + l4*16;
  const int aoff1 = (arow + 16 + l15)*1024 + l4*16;
  // staging: thread tid covers (gate=wid, unit=lane>>2, kq=lane&3); dst uniform-per-wave
  const size_t soff = ((size_t)wid*HID + u0 + (lane >> 2))*1024 + (lane & 3)*16;
  const int ldst = wid*1024;

  if (nht > 0){
    #pragma unroll
    for (int r=0;r<5;++r)
      GLL(wsl + soff + (size_t)r*WPLANE, Bl + r*4096 + ldst);
    __syncthreads();

    for (int t = 0; t < nht; ++t){
      const int cur = (t & 1)*20480;
      const int nxt = ((t+1) & 1)*20480;
      if (t+1 < nht){
        const size_t sk = soff + (size_t)(t+1)*64;
        #pragma unroll
        for (int r=0;r<5;++r)
          GLL(wsl + sk + (size_t)r*WPLANE, Bl + nxt + r*4096 + ldst);
      }
      i32x4 a0[5], a1[5];
      #pragma unroll
      for (int i=0;i<5;++i){
        a0[i] = *(const i32x4*)(hs + aoff0 + (size_t)i*hplane + t*64);
        a1[i] = *(const i32x4*)(hs + aoff1 + (size_t)i*hplane + t*64);
      }
      #pragma unroll
      for (int nt=0;nt<4;++nt){
        const int boff = cur + nt*1024 + l15*64 + l4*16;
        i32x4 b[5];
        #pragma unroll
        for (int j=0;j<5;++j)
          b[j] = *(const i32x4*)(Bl + boff + j*4096);
        MFMA15AB(acc[nt][0], a0, b);
        MFMA15AB(acc[nt][1], a1, b);
      }
      __syncthreads();   // drains global_load_lds (vmcnt) + guards buffer swap
    }
  }
  asm volatile("s_nop 7\ns_nop 7\ns_nop 7" ::);  // MFMA -> VALU read hazard guard

  const int u = u0 + l15;
  #pragma unroll
  for (int mt=0;mt<2;++mt){
    #pragma unroll
    for (int e=0;e<4;++e){
      const int r = r0 + wid*32 + mt*16 + l4*4 + e;
      const int tok = idx[r];
      const double* Er = E + (size_t)tok*G4;
      const double* Br = base + (size_t)r*G4;
      double pre[4];
      #pragma unroll
      for (int g=0;g<4;++g){
        double v = (double)acc[g][mt][4][e];
        v = v*0.00390625 + (double)acc[g][mt][3][e];
        v = v*0.00390625 + (double)acc[g][mt][2][e];
        v = v*0.00390625 + (double)acc[g][mt][1][e];
        v = v*0.00390625 + (double)acc[g][mt][0][e];
        pre[g] = v * 6.103515625e-05 + Er[g*HID+u] + Br[g*HID+u];   // 2^-14
      }
      double co = cst[(size_t)r*HID + u];
      double cn = dsig(pre[1])*co + dsig(pre[0])*dtanh_(pre[2]);
      double hn = dsig(pre[3])*dtanh_(cn);
      cst[(size_t)r*HID + u]  = cn;
      hout[(size_t)r*HID + u] = hn;
    }
  }
}

// ---------------- logits via i8 MFMA (15 pairs): lbuf[r][n] = (Wlin . h) ----------------
__global__ __launch_bounds__(256) void logits_i8(
    const signed char* __restrict__ hs, const signed char* __restrict__ wvl,
    double* __restrict__ lbuf, int hplane)
{
  const int tid = threadIdx.x;
  const int lane = tid & 63, wid = tid >> 6;
  const int l15 = lane & 15, l4 = lane >> 4;
  const int r0 = blockIdx.x*64, n0 = blockIdx.y*16;

  i32x4 acc[5];
  #pragma unroll
  for (int s=0;s<5;++s) acc[s] = (i32x4)(0);
  asm volatile("s_nop 3" ::);

  const int aoff = (r0 + wid*16 + l15)*1024 + l4*16;
  const int boff0 = (n0 + l15)*1024 + l4*16;

  for (int t = 0; t < 16; ++t){
    const int k0 = t*64;
    i32x4 a[5], b[5];
    #pragma unroll
    for (int i=0;i<5;++i)
      a[i] = *(const i32x4*)(hs + aoff + (size_t)i*hplane + k0);
    #pragma unroll
    for (int j=0;j<5;++j)
      b[j] = *(const i32x4*)(wvl + boff0 + (size_t)j*VLPLANE + k0);
    MFMA15AB(acc, a, b);
  }
  asm volatile("s_nop 7\ns_nop 7\ns_nop 7" ::);

  #pragma unroll
  for (int e=0;e<4;++e){
    double v = (double)acc[4][e];
    v = v*0.00390625 + (double)acc[3][e];
    v = v*0.00390625 + (double)acc[2][e];
    v = v*0.00390625 + (double)acc[1][e];
    v = v*0.00390625 + (double)acc[0][e];
    v *= 6.103515625e-05;
    const int r = r0 + wid*16 + l4*4 + e;
    lbuf[(size_t)r*HID + n0 + l15] = v;
  }
}

// ---------------- direct argmax ----------------
__global__ __launch_bounds__(256) void argmax_di(
    const double* __restrict__ lbuf, const float* __restrict__ blin,
    int* __restrict__ idx, float* __restrict__ outp, float* __restrict__ outi)
{
  const int tid = threadIdx.x;
  const int r = blockIdx.x*4 + (tid >> 6);
  const int lane = tid & 63;
  const double* lr = lbuf + (size_t)r*HID;
  double v[5];
  double m = -INFINITY; int am = 0;
  #pragma unroll
  for (int t=0;t<5;++t){
    int col = lane + 64*t;
    if (col < VOC){
      double x = lr[col] + (double)blin[col];
      v[t] = x;
      if (x > m){ m = x; am = col; }
    } else v[t] = -INFINITY;
  }
  #pragma unroll
  for (int d=1; d<64; d<<=1){
    double om = __shfl_xor(m, d, 64);
    int   oa = __shfl_xor(am, d, 64);
    if (om > m || (om == m && oa < am)){ m = om; am = oa; }
  }
  double s = 0.0;
  #pragma unroll
  for (int t=0;t<5;++t){
    int col = lane + 64*t;
    if (col < VOC) s += exp(v[t] - m);
  }
  #pragma unroll
  for (int d=1; d<64; d<<=1) s += __shfl_xor(s, d, 64);
  if (lane == 0){
    idx[r]  = am;
    outp[r] = (float)(1.0/s);
    outi[r] = (float)am;
  }
}

// ================= f64 fallback kernels =================

__global__ __launch_bounds__(256) void gates_v3(
    const double* __restrict__ hin, double* __restrict__ hout,
    double* __restrict__ cst, const int* __restrict__ idx,
    const double* __restrict__ E, const double* __restrict__ base,
    const float* __restrict__ Whh, const float* __restrict__ Wih,
    const float* __restrict__ wv,
    const float* __restrict__ bih, const float* __restrict__ bhh,
    int nht, int nwt)
{
  __shared__ double Al[32][132];
  __shared__ float  Bl[32][132];
  const int tid = threadIdx.x;
  const int r0 = blockIdx.x * 128;
  const int u0 = blockIdx.y * 32;
  const int tx = tid & 15, ty = tid >> 4;
  double acc[8][8];
  #pragma unroll
  for (int i=0;i<8;++i)
    #pragma unroll
    for (int j=0;j<8;++j) acc[i][j]=0.0;

  const int ra   = tid >> 1, kb16 = (tid & 1) * 16;
  const int cb   = ra;
  const int wrow = (cb >> 5)*HID + u0 + (cb & 31);

  for (int t = 0; t < nht + nwt; ++t){
    if (t < nht){
      int k0 = t*32;
      const double* s0 = hin + (size_t)(r0+ra)*HID + k0 + kb16;
      #pragma unroll
      for (int jj=0;jj<8;++jj){
        double2 v = *(const double2*)(s0 + 2*jj);
        Al[kb16+2*jj  ][ra] = v.x;
        Al[kb16+2*jj+1][ra] = v.y;
      }
      const float* s1 = Whh + (size_t)wrow*HID + k0 + kb16;
      #pragma unroll
      for (int jj=0;jj<4;++jj){
        float4 w = *(const float4*)(s1 + 4*jj);
        Bl[kb16+4*jj  ][cb] = w.x;
        Bl[kb16+4*jj+1][cb] = w.y;
        Bl[kb16+4*jj+2][cb] = w.z;
        Bl[kb16+4*jj+3][cb] = w.w;
      }
    } else {
      int k0 = (t - nht)*32;
      #pragma unroll
      for (int j=0;j<16;++j){
        int k = k0 + kb16 + j;
        Al[kb16+j][ra] = (k < WVD) ? (double)wv[(size_t)(r0+ra)*WVD + k] : 0.0;
        Bl[kb16+j][cb] = (k < WVD) ? Wih[(size_t)wrow*IND + EMB + k] : 0.f;
      }
    }
    __syncthreads();
    #pragma unroll
    for (int k=0;k<32;++k){
      double av[8], bv[8];
      #pragma unroll
      for (int i=0;i<8;++i) av[i] = Al[k][ty*8+i];
      #pragma unroll
      for (int j=0;j<8;++j) bv[j] = (double)Bl[k][tx + 16*j];
      #pragma unroll
      for (int i=0;i<8;++i)
        #pragma unroll
        for (int j=0;j<8;++j) acc[i][j] += av[i]*bv[j];
    }
    __syncthreads();
  }

  #pragma unroll
  for (int i=0;i<8;++i){
    int r = r0 + ty*8 + i;
    int tok = idx[r];
    const double* Er = E + (size_t)tok*G4;
    #pragma unroll
    for (int v=0;v<2;++v){
      int u = u0 + tx + 16*v;
      double pre[4];
      if (base){
        const double* Br = base + (size_t)r*G4;
        #pragma unroll
        for (int g=0;g<4;++g) pre[g] = acc[i][2*g+v] + Er[g*HID+u] + Br[g*HID+u];
      } else {
        #pragma unroll
        for (int g=0;g<4;++g) pre[g] = acc[i][2*g+v] + Er[g*HID+u]
                                     + (double)bih[g*HID+u] + (double)bhh[g*HID+u];
      }
      double co = cst[(size_t)r*HID + u];
      double cn = dsig(pre[1])*co + dsig(pre[0])*dtanh_(pre[2]);
      double hn = dsig(pre[3])*dtanh_(cn);
      cst[(size_t)r*HID + u]  = cn;
      hout[(size_t)r*HID + u] = hn;
    }
  }
}

__global__ __launch_bounds__(256) void logits_v3(
    const double* __restrict__ h, const float* __restrict__ Wlin,
    double* __restrict__ lbuf)
{
  __shared__ double Al[32][68];
  __shared__ float  Bl[32][68];
  const int tid = threadIdx.x;
  const int r0 = blockIdx.x*64, n0 = blockIdx.y*64, kk = blockIdx.z;
  const int kt0 = kk*11;
  const int kt1 = (kk==2) ? 32 : kt0 + 11;
  const int tx = tid & 15, ty = tid >> 4;
  double acc[4][4];
  #pragma unroll
  for (int i=0;i<4;++i)
    #pragma unroll
    for (int j=0;j<4;++j) acc[i][j]=0.0;

  const int ra = tid >> 2, kb8 = (tid & 3) * 8;
  const int wr = n0 + ra;
  const bool wok = (wr < VOC);
  for (int t = kt0; t < kt1; ++t){
    int k0 = t*32;
    const double* s0 = h + (size_t)(r0+ra)*HID + k0 + kb8;
    #pragma unroll
    for (int jj=0;jj<4;++jj){
      double2 v = *(const double2*)(s0 + 2*jj);
      Al[kb8+2*jj  ][ra] = v.x;
      Al[kb8+2*jj+1][ra] = v.y;
    }
    if (wok){
      const float* s1 = Wlin + (size_t)wr*HID + k0 + kb8;
      float4 w0 = *(const float4*)(s1+0);
      float4 w1 = *(const float4*)(s1+4);
      Bl[kb8+0][ra] = w0.x; Bl[kb8+1][ra] = w0.y;
      Bl[kb8+2][ra] = w0.z; Bl[kb8+3][ra] = w0.w;
      Bl[kb8+4][ra] = w1.x; Bl[kb8+5][ra] = w1.y;
      Bl[kb8+6][ra] = w1.z; Bl[kb8+7][ra] = w1.w;
    } else {
      #pragma unroll
      for (int j=0;j<8;++j) Bl[kb8+j][ra] = 0.f;
    }
    __syncthreads();
    #pragma unroll
    for (int k=0;k<32;++k){
      double av[4], bv[4];
      #pragma unroll
      for (int i=0;i<4;++i) av[i] = Al[k][ty*4+i];
      #pragma unroll
      for (int j=0;j<4;++j) bv[j] = (double)Bl[k][tx+16*j];
      #pragma unroll
      for (int i=0;i<4;++i)
        #pragma unroll
        for (int j=0;j<4;++j) acc[i][j] += av[i]*bv[j];
    }
    __syncthreads();
  }
  #pragma unroll
  for (int i=0;i<4;++i){
    int r = r0 + ty*4 + i;
    #pragma unroll
    for (int j=0;j<4;++j){
      int n = n0 + tx + 16*j;
      lbuf[(size_t)r*HID + kk*320 + n] = acc[i][j];
    }
  }
}

__global__ __launch_bounds__(256) void argmax_sk(
    const double* __restrict__ lbuf, const float* __restrict__ blin,
    int* __restrict__ idx, float* __restrict__ outp, float* __restrict__ outi)
{
  const int tid = threadIdx.x;
  const int r = blockIdx.x*4 + (tid >> 6);
  const int lane = tid & 63;
  const double* lr = lbuf + (size_t)r*HID;
  double v[5];
  double m = -INFINITY; int am = 0;
  #pragma unroll
  for (int t=0;t<5;++t){
    int col = lane + 64*t;
    if (col < VOC){
      double x = ((lr[col] + lr[320+col]) + lr[640+col]) + (double)blin[col];
      v[t] = x;
      if (x > m){ m = x; am = col; }
    } else v[t] = -INFINITY;
  }
  #pragma unroll
  for (int d=1; d<64; d<<=1){
    double om = __shfl_xor(m, d, 64);
    int   oa = __shfl_xor(am, d, 64);
    if (om > m || (om == m && oa < am)){ m = om; am = oa; }
  }
  double s = 0.0;
  #pragma unroll
  for (int t=0;t<5;++t){
    int col = lane + 64*t;
    if (col < VOC) s += exp(v[t] - m);
  }
  #pragma unroll
  for (int d=1; d<64; d<<=1) s += __shfl_xor(s, d, 64);
  if (lane == 0){
    idx[r]  = am;
    outp[r] = (float)(1.0/s);
    outi[r] = (float)am;
  }
}

// ======================= launch =======================

extern "C" void kernel_launch(void* const* d_in, const int* in_sizes, int n_in,
                              void* d_out, int out_size, void* d_ws, size_t ws_size,
                              hipStream_t stream){
  const float* wv   = (const float*)d_in[0];
  const float* emb  = (const float*)d_in[1];
  const float* Wih  = (const float*)d_in[2];
  const float* Whh  = (const float*)d_in[3];
  const float* bih  = (const float*)d_in[4];
  const float* bhh  = (const float*)d_in[5];
  const float* Wlin = (const float*)d_in[6];
  const float* blin = (const float*)d_in[7];
  float* out = (float*)d_out;

  char* w = (char*)d_ws;
  size_t off = 0;
  auto al = [](size_t b){ return (b + 255) & ~(size_t)255; };
  auto alloc = [&](size_t bytes) -> void* {
    void* p = w + off; off += al(bytes); return p;
  };

  const size_t fixed = al((size_t)VOC*G4*8) + al((size_t)BS*4);

  int R = 0; int mode = 0;
  for (int r = 4096; r >= 2048; r >>= 1){
    size_t need = fixed + 3*al((size_t)r*HID*8) + al((size_t)r*G4*8)
                + al((size_t)5*r*HID) + al((size_t)5*WPLANE) + al((size_t)5*VLPLANE);
    if (need <= ws_size){ R = r; mode = 2; break; }
  }
  if (!R){
    for (int r = 4096; r >= 1024; r >>= 1){
      if (fixed + 3*al((size_t)r*HID*8) + al((size_t)r*G4*8) <= ws_size){ R = r; mode = 1; break; }
    }
  }
  if (!R){
    for (int r = 8192; r >= 256; r >>= 1){
      if (fixed + 3*al((size_t)r*HID*8) <= ws_size){ R = r; mode = 0; break; }
    }
  }
  if (!R) return;

  double* Ed  = (double*)alloc((size_t)VOC*G4*8);
  int*    idx = (int*)   alloc((size_t)BS*4);
  double* h0  = (double*)alloc((size_t)R*HID*8);
  double* h1  = (double*)alloc((size_t)R*HID*8);
  double* cd  = (double*)alloc((size_t)R*HID*8);
  double* base = (mode >= 1) ? (double*)alloc((size_t)R*G4*8) : nullptr;
  signed char* hs  = (mode == 2) ? (signed char*)alloc((size_t)5*R*HID) : nullptr;
  signed char* wsl = (mode == 2) ? (signed char*)alloc((size_t)5*WPLANE) : nullptr;
  signed char* wvl = (mode == 2) ? (signed char*)alloc((size_t)5*VLPLANE) : nullptr;

  hipMemsetAsync(idx, 0, (size_t)BS*4, stream);
  ekernel_f64<<<dim3(16,17),256,0,stream>>>(emb, Wih, Ed);
  if (mode == 2){
    wslice<<<WPLANE/1024,256,0,stream>>>(Whh, wsl, WPLANE);
    hipMemsetAsync(wvl, 0, (size_t)5*VLPLANE, stream);
    wslice<<<(VOC*HID)/1024,256,0,stream>>>(Wlin, wvl, VLPLANE);
  }

  const int hplane = R*HID;
  for (int c0 = 0; c0 < BS; c0 += R){
    if (mode >= 1)
      base_v3<<<dim3(R/128, 32),256,0,stream>>>(wv + (size_t)c0*WVD, Wih, bih, bhh, base);
    hipMemsetAsync(cd, 0, (size_t)R*HID*8, stream);
    double* hb[2] = {h0, h1};
    for (int s = 0; s < NST; ++s){
      if (mode == 2){
        gates_i8<<<dim3(R/128, 64),256,0,stream>>>(
            hs, wsl, hb[(s+1)&1], cd, idx + c0, Ed, base,
            (s==0) ? 0 : HID/64, hplane, R/128);
        slice_h<<<R/2,256,0,stream>>>(hb[(s+1)&1], hs, hplane);
        logits_i8<<<dim3(R/64, VOCP/16),256,0,stream>>>(
            hs, wvl, hb[s&1], hplane);
        argmax_di<<<R/4,256,0,stream>>>(
            hb[s&1], blin, idx + c0,
            out + (size_t)s*BS + c0, out + (size_t)NST*BS + (size_t)s*BS + c0);
      } else {
        gates_v3<<<dim3(R/128, 32),256,0,stream>>>(
            hb[s&1], hb[(s+1)&1], cd, idx + c0, Ed, base,
            Whh, Wih, wv + (size_t)c0*WVD, bih, bhh,
            (s==0) ? 0 : HID/32, (mode==1) ? 0 : 10);
        logits_v3<<<dim3(R/64, 5, 3),256,0,stream>>>(
            hb[(s+1)&1], Wlin, hb[s&1]);
        argmax_sk<<<R/4,256,0,stream>>>(
            hb[s&1], blin, idx + c0,
            out + (size_t)s*BS + c0, out + (size_t)NST*BS + (size_t)s*BS + c0);
      }
    }
  }
}